// Round 2
// baseline (671.451 us; speedup 1.0000x reference)
//
#include <hip/hip_runtime.h>
#include <cmath>

// ============================================================================
// AutoregressiveGroupQuerySelfAttention  (B=2, S=2048, H=2048, nH=16, D=128)
//
// Round 6: attn rewritten to 32x32x16 MFMA with swapped operands (m214-style).
//  - S^T = mfma(K, Q): lane owns q-column -> lane-local online softmax
//    (31 fmax + one shfl_xor(32)), no Ps LDS buffer.
//  - P -> PV B-frag via v_cvt_pk_bf16_f32 + v_permlane32_swap_b32 (in-register).
//  - O^T = mfma(V^T, P): rescale/normalize lane-local; epilogue transposes
//    through LDS for coalesced stores.
//  - K/V LDS tiles XOR-swizzled (idx ^ ((row&7)<<3)) on both write and read
//    (reg-staged commit, so both-sides swizzle is legal).
//  - 256-thread blocks (4 waves x 32 q-rows = 128-row q-tile), grid(16,16,2),
//    z-complementary qt pairing kept. LDS 48KB, ~230 VGPR target (no spill).
//  - GEMM path unchanged from round 5.
// ============================================================================

typedef unsigned short u16;
typedef __attribute__((ext_vector_type(4))) float  f32x4;
typedef __attribute__((ext_vector_type(16))) float f32x16;
typedef __attribute__((ext_vector_type(4))) float  float4v;
typedef __attribute__((ext_vector_type(4))) unsigned short u16x4;
typedef __attribute__((ext_vector_type(8))) unsigned short u16x8;
typedef __attribute__((ext_vector_type(8))) short s16x8;

__device__ __forceinline__ u16 f2bf(float f) {
  unsigned u = __float_as_uint(f);
  u += 0x7FFFu + ((u >> 16) & 1u);            // RNE; inputs are finite
  return (u16)(u >> 16);
}
__device__ __forceinline__ float bf2f(u16 h) {
  return __uint_as_float(((unsigned)h) << 16);
}
__device__ __forceinline__ f32x4 MFMA(s16x8 a, s16x8 b, f32x4 c) {
  return __builtin_amdgcn_mfma_f32_16x16x32_bf16(a, b, c, 0, 0, 0);
}
__device__ __forceinline__ f32x16 MFMA32(s16x8 a, s16x8 b, f32x16 c) {
  return __builtin_amdgcn_mfma_f32_32x32x16_bf16(a, b, c, 0, 0, 0);
}
__device__ __forceinline__ unsigned cvtpk_bf16(float lo, float hi) {
  unsigned r;
  asm("v_cvt_pk_bf16_f32 %0, %1, %2" : "=v"(r) : "v"(lo), "v"(hi));
  return r;
}
// async global->LDS, 16B per lane; LDS dest = wave-uniform base + lane*16
__device__ __forceinline__ void gld16(const void* g, void* s) {
  __builtin_amdgcn_global_load_lds(
      (const __attribute__((address_space(1))) void*)g,
      (__attribute__((address_space(3))) void*)s, 16, 0, 0);
}

// ---------------------------------------------------------------------------
// fp32 -> bf16 hi (+ optional lo residual).  n4 = element count / 4.
// ---------------------------------------------------------------------------
__global__ void split_bf16(const float* __restrict__ src, u16* __restrict__ hi,
                           u16* __restrict__ lo, int n4) {
  int i = blockIdx.x * 256 + threadIdx.x;
  if (i >= n4) return;
  float4v v = ((const float4v*)src)[i];
  u16x4 hv, lv;
#pragma unroll
  for (int j = 0; j < 4; ++j) {
    float f = v[j];
    u16 h = f2bf(f);
    hv[j] = h;
    lv[j] = f2bf(f - bf2f(h));
  }
  ((u16x4*)hi)[i] = hv;
  if (lo) ((u16x4*)lo)[i] = lv;
}

// ---------------------------------------------------------------------------
// RoPE tables in fp64.
// ---------------------------------------------------------------------------
__global__ void rope_tab(float* __restrict__ cosT, float* __restrict__ sinT) {
  int idx = blockIdx.x * 256 + threadIdx.x;   // 2048*64
  int i = idx & 63, s = idx >> 6;
  double invf = pow(10000.0, -(double)i / 64.0);
  double ang = (double)s * invf;
  cosT[idx] = (float)cos(ang);
  sinT[idx] = (float)sin(ang);
}

// ---------------------------------------------------------------------------
// GEMM  C(MxN) = A(MxK) * B(NxK)^T, bf16 inputs, fp32 accumulate.
// NTERM==3: split precision (hh+hl+lh).
// OMODE: 0 fp32, 1 bf16 hi/lo, 2 bf16.   ROPE: fuse rotation in epilogue.
// 128x128 tile, BK=32, 4 waves each 32(m) x 128(n): acc[2][8].
// Staging via global_load_lds (16B/lane), unpadded LDS [128][32].
// ---------------------------------------------------------------------------
template <int NTERM, int OMODE, int ROPE>
__global__ __launch_bounds__(256, 3)
void gemm_bt(const u16* __restrict__ Ah, const u16* __restrict__ Al,
             const u16* __restrict__ Bh, const u16* __restrict__ Bl,
             float* __restrict__ Cf, u16* __restrict__ Ch, u16* __restrict__ Cl,
             const float* __restrict__ cosT, const float* __restrict__ sinT,
             float scale, int M, int N, int K) {
  __shared__ u16 As[128 * 32];
  __shared__ u16 Bs[128 * 32];
  __shared__ u16 Asl[NTERM == 3 ? 128 * 32 : 8];
  __shared__ u16 Bsl[NTERM == 3 ? 128 * 32 : 8];
  const int bn = blockIdx.x, bm = blockIdx.y;
  const int t = threadIdx.x;
  const int w = t >> 6, lane = t & 63, quad = lane >> 4, lc = lane & 15;

  const f32x4 ZERO = {0.f, 0.f, 0.f, 0.f};
  f32x4 acc[2][8];
#pragma unroll
  for (int i = 0; i < 2; ++i)
#pragma unroll
    for (int j = 0; j < 8; ++j) acc[i][j] = ZERO;

  const int sr0 = (lane >> 2);
  const int sc0 = (lane & 3) * 8;
  const size_t arow0 = (size_t)bm * 128, brow0 = (size_t)bn * 128;

  for (int k0 = 0; k0 < K; k0 += 32) {
#pragma unroll
    for (int p = 0; p < 2; ++p) {
      const int ch = 2 * w + p;
      const int r = ch * 16 + sr0;
      const size_t ga = (arow0 + r) * (size_t)K + k0 + sc0;
      const size_t gb = (brow0 + r) * (size_t)K + k0 + sc0;
      const int ldso = ch * 512 + lane * 8;   // u16 index
      gld16(&Ah[ga], &As[ldso]);
      gld16(&Bh[gb], &Bs[ldso]);
      if constexpr (NTERM == 3) {
        gld16(&Al[ga], &Asl[ldso]);
        gld16(&Bl[gb], &Bsl[ldso]);
      }
    }
    __syncthreads();

    s16x8 ah[2], al[2];
#pragma unroll
    for (int i = 0; i < 2; ++i) {
      ah[i] = *(const s16x8*)&As[(32 * w + 16 * i + lc) * 32 + 8 * quad];
      if constexpr (NTERM == 3)
        al[i] = *(const s16x8*)&Asl[(32 * w + 16 * i + lc) * 32 + 8 * quad];
    }
#pragma unroll
    for (int j = 0; j < 8; ++j) {
      const s16x8 bh = *(const s16x8*)&Bs[(16 * j + lc) * 32 + 8 * quad];
      s16x8 bl;
      if constexpr (NTERM == 3)
        bl = *(const s16x8*)&Bsl[(16 * j + lc) * 32 + 8 * quad];
#pragma unroll
      for (int i = 0; i < 2; ++i) {
        acc[i][j] = MFMA(ah[i], bh, acc[i][j]);
        if constexpr (NTERM == 3) {
          acc[i][j] = MFMA(ah[i], bl, acc[i][j]);
          acc[i][j] = MFMA(al[i], bh, acc[i][j]);
        }
      }
    }
    __syncthreads();
  }

  // ---- epilogue ----
  if constexpr (ROPE) {
    // N-tile 128 == one head (bn*128 head-aligned). Pair cols d and d+64.
#pragma unroll
    for (int i = 0; i < 2; ++i)
#pragma unroll
      for (int r = 0; r < 4; ++r) {
        const int row = bm * 128 + 32 * w + 16 * i + 4 * quad + r;
        const int s = row & 2047;
#pragma unroll
        for (int j = 0; j < 4; ++j) {
          const int hd = 16 * j + lc;
          const float cs = cosT[s * 64 + hd], sn = sinT[s * 64 + hd];
          const float q1 = acc[i][j][r], q2 = acc[i][j + 4][r];
          const float o1 = (q1 * cs - q2 * sn) * scale;
          const float o2 = (q2 * cs + q1 * sn) * scale;
          const size_t p1 = (size_t)row * N + bn * 128 + hd;
          const u16 h1 = f2bf(o1);
          Ch[p1] = h1; Cl[p1] = f2bf(o1 - bf2f(h1));
          const u16 h2 = f2bf(o2);
          Ch[p1 + 64] = h2; Cl[p1 + 64] = f2bf(o2 - bf2f(h2));
        }
      }
  } else {
#pragma unroll
    for (int i = 0; i < 2; ++i)
#pragma unroll
      for (int j = 0; j < 8; ++j) {
        const int col = bn * 128 + 16 * j + lc;
#pragma unroll
        for (int r = 0; r < 4; ++r) {
          const int row = bm * 128 + 32 * w + 16 * i + 4 * quad + r;
          const float v = acc[i][j][r];
          if constexpr (OMODE == 0) {
            Cf[(size_t)row * N + col] = v;
          } else if constexpr (OMODE == 1) {
            const u16 hv = f2bf(v);
            Ch[(size_t)row * N + col] = hv;
            Cl[(size_t)row * N + col] = f2bf(v - bf2f(hv));
          } else {
            Ch[(size_t)row * N + col] = f2bf(v);
          }
        }
      }
  }
}

// ---------------------------------------------------------------------------
// Flash attention, causal, 32x32x16 MFMA, swapped operands.
// Q pre-scaled by sqrt(D) (folded into Q-GEMM epilogue).
// grid (16 x, 16 heads, 2 batches), qt = z ? x : 15-x (complementary pairing).
// 256 threads = 4 waves; wave w owns q-rows [qt*128+32w, +32). KVBLK=64.
// Per wave: S^T = mfma(K, Q) -> lane owns q-col (q = qt*128+32w+(lane&31));
// online softmax lane-local (+shfl_xor 32 to combine k-halves);
// P repacked in-register via cvt_pk_bf16 + permlane32_swap;
// O^T += mfma(V^T, P) -> rescale/normalize lane-local.
// LDS: Ksh/Ksl 64x128, Vts 128x64, XOR-swizzled rows (idx ^ ((row&7)<<3)),
// total 48KB; epilogue reuses LDS to transpose O^T for coalesced stores.
// ---------------------------------------------------------------------------
__global__ __launch_bounds__(256, 2)
void attn(const u16* __restrict__ Qh, const u16* __restrict__ Ql,
          const u16* __restrict__ Kh, const u16* __restrict__ Kl,
          const u16* __restrict__ Vt, u16* __restrict__ Ctx) {
  __shared__ u16 SMEM[24576];               // 48 KB
  u16* Ksh = SMEM;                          // [64][128] swizzled
  u16* Ksl = SMEM + 8192;                   // [64][128] swizzled
  u16* Vts = SMEM + 16384;                  // [128][64] swizzled

  const int qt = blockIdx.z ? (int)blockIdx.x : 15 - (int)blockIdx.x;
  const int h = blockIdx.y, b = blockIdx.z;
  const int t = threadIdx.x;
  const int w = t >> 6, lane = t & 63;
  const int l31 = lane & 31, hi = lane >> 5;
  const int swz = (l31 & 7) << 3;           // row-swizzle for this lane's reads
  const int qg = qt * 128 + 32 * w + l31;   // this lane's q row (within seq)

  // ---- Q B-fragments in registers: Q[q=qg][d = 16s + 8hi + j] ----
  s16x8 qfh[8], qfl[8];
  {
    const size_t qbase =
        ((size_t)(b * 2048 + qg)) * 2048 + h * 128 + 8 * hi;
#pragma unroll
    for (int s = 0; s < 8; ++s) {
      qfh[s] = *(const s16x8*)&Qh[qbase + 16 * s];
      qfl[s] = *(const s16x8*)&Ql[qbase + 16 * s];
    }
  }

  float m_run = -3.0e38f, l_run = 0.f;
  f32x16 o[4];
#pragma unroll
  for (int d = 0; d < 4; ++d)
#pragma unroll
    for (int r = 0; r < 16; ++r) o[d][r] = 0.f;

  const u16* gKh0 = Kh + ((size_t)(b * 2048)) * 2048 + h * 128;
  const u16* gKl0 = Kl + ((size_t)(b * 2048)) * 2048 + h * 128;
  const u16* gV0  = Vt + (size_t)(h * 128) * 4096 + b * 2048;  // row stride 4096

  const int ktmax = 2 * qt + 1;
  // staging maps (256 threads)
  const int kr = t >> 2, kc = (t & 3) * 32;   // K: row 0..63, col base
  const int vr = t >> 1, vc = (t & 1) * 32;   // V: row 0..127, col base

  u16x8 pKh[4], pKl[4], pV[4];
  // ---- prefetch tile 0 ----
#pragma unroll
  for (int p = 0; p < 4; ++p) {
    pKh[p] = *(const u16x8*)&gKh0[(size_t)kr * 2048 + kc + 8 * p];
    pKl[p] = *(const u16x8*)&gKl0[(size_t)kr * 2048 + kc + 8 * p];
    pV[p]  = *(const u16x8*)&gV0[(size_t)vr * 4096 + vc + 8 * p];
  }

  for (int kt = 0; kt <= ktmax; ++kt) {
    // ---- commit prefetched tile to LDS (swizzled) ----
#pragma unroll
    for (int p = 0; p < 4; ++p) {
      *(u16x8*)&Ksh[(kr * 128 + kc + 8 * p) ^ ((kr & 7) << 3)] = pKh[p];
      *(u16x8*)&Ksl[(kr * 128 + kc + 8 * p) ^ ((kr & 7) << 3)] = pKl[p];
      *(u16x8*)&Vts[(vr * 64 + vc + 8 * p) ^ ((vr & 7) << 3)] = pV[p];
    }
    __syncthreads();

    // ---- prefetch next tile ----
    if (kt < ktmax) {
#pragma unroll
      for (int p = 0; p < 4; ++p) {
        pKh[p] = *(const u16x8*)&gKh0[(size_t)((kt + 1) * 64 + kr) * 2048 + kc + 8 * p];
        pKl[p] = *(const u16x8*)&gKl0[(size_t)((kt + 1) * 64 + kr) * 2048 + kc + 8 * p];
        pV[p]  = *(const u16x8*)&gV0[(size_t)vr * 4096 + (kt + 1) * 64 + vc + 8 * p];
      }
    }

    const bool active = (qt * 128 + 32 * w + 31) >= kt * 64;
    if (active) {
      // ---- S^T = K * Q^T (split precision, 3-term) ----
      f32x16 acc0, acc1;
#pragma unroll
      for (int r = 0; r < 16; ++r) { acc0[r] = 0.f; acc1[r] = 0.f; }
      __builtin_amdgcn_s_setprio(1);
#pragma unroll
      for (int s = 0; s < 8; ++s) {
        const int col = 16 * s + 8 * hi;
        const s16x8 k0h = *(const s16x8*)&Ksh[((l31) * 128 + col) ^ swz];
        const s16x8 k0l = *(const s16x8*)&Ksl[((l31) * 128 + col) ^ swz];
        acc0 = MFMA32(k0h, qfh[s], acc0);
        acc0 = MFMA32(k0l, qfh[s], acc0);
        acc0 = MFMA32(k0h, qfl[s], acc0);
        const s16x8 k1h = *(const s16x8*)&Ksh[((32 + l31) * 128 + col) ^ swz];
        const s16x8 k1l = *(const s16x8*)&Ksl[((32 + l31) * 128 + col) ^ swz];
        acc1 = MFMA32(k1h, qfh[s], acc1);
        acc1 = MFMA32(k1l, qfh[s], acc1);
        acc1 = MFMA32(k1h, qfl[s], acc1);
      }
      __builtin_amdgcn_s_setprio(0);

      // ---- causal mask + online softmax (lane-local; q = qg) ----
      const int kb0 = kt * 64;
      const bool partial = (kt * 64 + 63) > (qt * 128 + 32 * w);  // wave-uniform
      float mx = -3.0e38f;
#pragma unroll
      for (int r = 0; r < 16; ++r) {
        const int koff = (r & 3) + 8 * (r >> 2) + 4 * hi;
        float v0 = acc0[r], v1 = acc1[r];
        if (partial) {
          if (kb0 + koff > qg) v0 = -3.0e38f;
          if (kb0 + 32 + koff > qg) v1 = -3.0e38f;
        }
        acc0[r] = v0; acc1[r] = v1;
        mx = fmaxf(mx, fmaxf(v0, v1));
      }
      mx = fmaxf(mx, __shfl_xor(mx, 32));      // combine k-halves (same q)
      const float mn = fmaxf(m_run, mx);
      const float al = __expf(m_run - mn);
      m_run = mn;
      float rs = 0.f;
#pragma unroll
      for (int r = 0; r < 16; ++r) {
        const float e0 = __expf(acc0[r] - mn);
        const float e1 = __expf(acc1[r] - mn);
        acc0[r] = e0; acc1[r] = e1;
        rs += e0 + e1;
      }
      rs += __shfl_xor(rs, 32);
      l_run = l_run * al + rs;
#pragma unroll
      for (int d = 0; d < 4; ++d)
#pragma unroll
        for (int r = 0; r < 16; ++r) o[d][r] *= al;

      // ---- pack P -> PV B-fragments (cvt_pk + permlane32_swap) ----
      s16x8 pb[4];
#pragma unroll
      for (int tt = 0; tt < 4; ++tt) {
        const int q2A = 2 * (tt & 1);
        float e0, e1, e2, e3, f0, f1, f2, f3;
        if (tt < 2) {
          e0 = acc0[4 * q2A + 0]; e1 = acc0[4 * q2A + 1];
          e2 = acc0[4 * q2A + 2]; e3 = acc0[4 * q2A + 3];
          f0 = acc0[4 * q2A + 4]; f1 = acc0[4 * q2A + 5];
          f2 = acc0[4 * q2A + 6]; f3 = acc0[4 * q2A + 7];
        } else {
          e0 = acc1[4 * q2A + 0]; e1 = acc1[4 * q2A + 1];
          e2 = acc1[4 * q2A + 2]; e3 = acc1[4 * q2A + 3];
          f0 = acc1[4 * q2A + 4]; f1 = acc1[4 * q2A + 5];
          f2 = acc1[4 * q2A + 6]; f3 = acc1[4 * q2A + 7];
        }
        unsigned a0 = cvtpk_bf16(e0, e1);
        unsigned a1 = cvtpk_bf16(e2, e3);
        unsigned b0 = cvtpk_bf16(f0, f1);
        unsigned b1 = cvtpk_bf16(f2, f3);
        asm volatile("v_permlane32_swap_b32 %0, %1" : "+v"(a0), "+v"(b0));
        asm volatile("v_permlane32_swap_b32 %0, %1" : "+v"(a1), "+v"(b1));
        union { unsigned u[4]; s16x8 v; } pk;
        pk.u[0] = a0; pk.u[1] = a1; pk.u[2] = b0; pk.u[3] = b1;
        pb[tt] = pk.v;
      }

      // ---- O^T += V^T * P ----
      __builtin_amdgcn_s_setprio(1);
#pragma unroll
      for (int d = 0; d < 4; ++d) {
#pragma unroll
        for (int tt = 0; tt < 4; ++tt) {
          const s16x8 va =
              *(const s16x8*)&Vts[((32 * d + l31) * 64 + 16 * tt + 8 * hi) ^ swz];
          o[d] = MFMA32(va, pb[tt], o[d]);
        }
      }
      __builtin_amdgcn_s_setprio(0);
    }
    __syncthreads();   // protect K/V tiles before next commit
  }

  // ---- epilogue: normalize, transpose O^T -> O via LDS, coalesced store ----
  const float inv_l = 1.0f / l_run;
  u16* Os = SMEM;                            // [128][128] swizzled
  const int qrow = 32 * w + l31;
#pragma unroll
  for (int d = 0; d < 4; ++d)
#pragma unroll
    for (int r = 0; r < 16; r += 2) {
      const int dd = 32 * d + (r & 3) + 8 * (r >> 2) + 4 * hi;
      const unsigned pr = cvtpk_bf16(o[d][r] * inv_l, o[d][r + 1] * inv_l);
      *(unsigned*)&Os[(qrow * 128 + dd) ^ ((qrow & 7) << 3)] = pr;
    }
  __syncthreads();
  {
    const int row = t >> 1, c0 = (t & 1) * 64;
    const size_t obase =
        ((size_t)(b * 2048 + qt * 128 + row)) * 2048 + h * 128 + c0;
#pragma unroll
    for (int p = 0; p < 8; ++p)
      *(u16x8*)&Ctx[obase + 8 * p] =
          *(const u16x8*)&Os[(row * 128 + c0 + 8 * p) ^ ((row & 7) << 3)];
  }
}

// ---------------------------------------------------------------------------
extern "C" void kernel_launch(void* const* d_in, const int* in_sizes, int n_in,
                              void* d_out, int out_size, void* d_ws, size_t ws_size,
                              hipStream_t stream) {
  const float* x  = (const float*)d_in[0];
  const float* Wq = (const float*)d_in[1];
  const float* Wk = (const float*)d_in[2];
  const float* Wv = (const float*)d_in[3];
  const float* Wo = (const float*)d_in[4];
  float* out = (float*)d_out;

  char* ws = (char*)d_ws;
  size_t off = 0;
  auto alloc = [&](size_t bytes) {
    char* p = ws + off;
    off += (bytes + 255) & ~(size_t)255;
    return p;
  };
  const size_t XE = (size_t)4096 * 2048;   // B*S x H elements
  const size_t WE = (size_t)2048 * 2048;

  u16* xh  = (u16*)alloc(XE * 2);
  u16* xl  = (u16*)alloc(XE * 2);
  u16* Wqh = (u16*)alloc(WE * 2);
  u16* Wql = (u16*)alloc(WE * 2);
  u16* Wkh = (u16*)alloc(WE * 2);
  u16* Wkl = (u16*)alloc(WE * 2);
  u16* Wvh = (u16*)alloc(WE * 2);
  u16* Woh = (u16*)alloc(WE * 2);
  u16* Qhb = (u16*)alloc(XE * 2);
  u16* Qlb = (u16*)alloc(XE * 2);
  u16* Khb = (u16*)alloc(XE * 2);
  u16* Klb = (u16*)alloc(XE * 2);
  u16* Vtb = (u16*)alloc(XE * 2);   // V^T: [2048 dims][4096 seq]
  u16* Ctxb = (u16*)alloc(XE * 2);
  float* cosT = (float*)alloc((size_t)2048 * 64 * 4);
  float* sinT = (float*)alloc((size_t)2048 * 64 * 4);
  (void)ws_size;  // requires ~170 MB of workspace
  (void)in_sizes; (void)n_in; (void)out_size;

  // 1) precision split + RoPE tables
  split_bf16<<<8192, 256, 0, stream>>>(x, xh, xl, (int)(XE / 4));
  split_bf16<<<4096, 256, 0, stream>>>(Wq, Wqh, Wql, (int)(WE / 4));
  split_bf16<<<4096, 256, 0, stream>>>(Wk, Wkh, Wkl, (int)(WE / 4));
  split_bf16<<<4096, 256, 0, stream>>>(Wv, Wvh, nullptr, (int)(WE / 4));
  split_bf16<<<4096, 256, 0, stream>>>(Wo, Woh, nullptr, (int)(WE / 4));
  rope_tab<<<512, 256, 0, stream>>>(cosT, sinT);

  // 2) projections: Q,K split-precision with fused RoPE; V^T directly
  gemm_bt<3, 1, 1><<<dim3(16, 32), 256, 0, stream>>>(
      xh, xl, Wqh, Wql, nullptr, Qhb, Qlb, cosT, sinT,
      11.313708498984760f, 4096, 2048, 2048);
  gemm_bt<3, 1, 1><<<dim3(16, 32), 256, 0, stream>>>(
      xh, xl, Wkh, Wkl, nullptr, Khb, Klb, cosT, sinT,
      1.0f, 4096, 2048, 2048);
  // V^T = Wv * x^T :  A=Wv (M=2048 dims), B=x (N=4096 seq)
  gemm_bt<1, 2, 0><<<dim3(32, 16), 256, 0, stream>>>(
      Wvh, nullptr, xh, nullptr, nullptr, Vtb, nullptr, nullptr, nullptr,
      1.0f, 2048, 4096, 2048);

  // 3) causal flash attention (32x32 swapped-operand structure)
  attn<<<dim3(16, 16, 2), 256, 0, stream>>>(Qhb, Qlb, Khb, Klb, Vtb, Ctxb);

  // 4) output projection -> fp32 d_out
  gemm_bt<1, 0, 0><<<dim3(16, 32), 256, 0, stream>>>(
      Ctxb, nullptr, Woh, nullptr, out, nullptr, nullptr, nullptr, nullptr,
      1.0f, 4096, 2048, 2048);
}

// Round 3
// 643.853 us; speedup vs baseline: 1.0429x; 1.0429x over previous
//
#include <hip/hip_runtime.h>
#include <cmath>

// ============================================================================
// AutoregressiveGroupQuerySelfAttention  (B=2, S=2048, H=2048, nH=16, D=128)
//
// Round 7: attn -> counted-vmcnt double-buffered pipeline (T3/T4).
//  - QBLK=256, 8 waves (512 thr), grid (8,16,2) = 256 blocks = 1/CU.
//    Each block runs TWO tasks: (b=z, qt=x) then (b=1-z, qt=7-x) -> uniform
//    36 k-steps/block (no causal tail imbalance).
//  - K/V staged via global_load_lds (16B) into 2x48KB LDS buffers; global
//    source pre-swizzled with the same XOR involution the reads use
//    (LDS dest stays linear -> both-sides swizzle preserved, rule 21).
//  - Raw s_barrier + s_waitcnt vmcnt(6): stage(t+1) stays in flight across
//    barriers; vmcnt never drained mid-loop. Next task's first stage issues
//    before the previous task's epilogue.
//  - 32x32x16 swapped-operand MFMA structure kept from round 6 (lane-local
//    softmax, cvt_pk+permlane32_swap P-repack, O^T via LDS transpose).
//  - XCD-bijective block remap: all 16 blocks of a head on one XCD's L2.
//  - GEMM path unchanged.
// ============================================================================

typedef unsigned short u16;
typedef __attribute__((ext_vector_type(4))) float  f32x4;
typedef __attribute__((ext_vector_type(16))) float f32x16;
typedef __attribute__((ext_vector_type(4))) float  float4v;
typedef __attribute__((ext_vector_type(4))) unsigned short u16x4;
typedef __attribute__((ext_vector_type(8))) unsigned short u16x8;
typedef __attribute__((ext_vector_type(8))) short s16x8;

__device__ __forceinline__ u16 f2bf(float f) {
  unsigned u = __float_as_uint(f);
  u += 0x7FFFu + ((u >> 16) & 1u);            // RNE; inputs are finite
  return (u16)(u >> 16);
}
__device__ __forceinline__ float bf2f(u16 h) {
  return __uint_as_float(((unsigned)h) << 16);
}
__device__ __forceinline__ f32x4 MFMA(s16x8 a, s16x8 b, f32x4 c) {
  return __builtin_amdgcn_mfma_f32_16x16x32_bf16(a, b, c, 0, 0, 0);
}
__device__ __forceinline__ f32x16 MFMA32(s16x8 a, s16x8 b, f32x16 c) {
  return __builtin_amdgcn_mfma_f32_32x32x16_bf16(a, b, c, 0, 0, 0);
}
__device__ __forceinline__ unsigned cvtpk_bf16(float lo, float hi) {
  unsigned r;
  asm("v_cvt_pk_bf16_f32 %0, %1, %2" : "=v"(r) : "v"(lo), "v"(hi));
  return r;
}
// async global->LDS, 16B per lane; LDS dest = wave-uniform base + lane*16
__device__ __forceinline__ void gld16(const void* g, void* s) {
  __builtin_amdgcn_global_load_lds(
      (const __attribute__((address_space(1))) void*)g,
      (__attribute__((address_space(3))) void*)s, 16, 0, 0);
}

// ---------------------------------------------------------------------------
// fp32 -> bf16 hi (+ optional lo residual).  n4 = element count / 4.
// ---------------------------------------------------------------------------
__global__ void split_bf16(const float* __restrict__ src, u16* __restrict__ hi,
                           u16* __restrict__ lo, int n4) {
  int i = blockIdx.x * 256 + threadIdx.x;
  if (i >= n4) return;
  float4v v = ((const float4v*)src)[i];
  u16x4 hv, lv;
#pragma unroll
  for (int j = 0; j < 4; ++j) {
    float f = v[j];
    u16 h = f2bf(f);
    hv[j] = h;
    lv[j] = f2bf(f - bf2f(h));
  }
  ((u16x4*)hi)[i] = hv;
  if (lo) ((u16x4*)lo)[i] = lv;
}

// ---------------------------------------------------------------------------
// RoPE tables in fp64.
// ---------------------------------------------------------------------------
__global__ void rope_tab(float* __restrict__ cosT, float* __restrict__ sinT) {
  int idx = blockIdx.x * 256 + threadIdx.x;   // 2048*64
  int i = idx & 63, s = idx >> 6;
  double invf = pow(10000.0, -(double)i / 64.0);
  double ang = (double)s * invf;
  cosT[idx] = (float)cos(ang);
  sinT[idx] = (float)sin(ang);
}

// ---------------------------------------------------------------------------
// GEMM  C(MxN) = A(MxK) * B(NxK)^T, bf16 inputs, fp32 accumulate.
// NTERM==3: split precision (hh+hl+lh).
// OMODE: 0 fp32, 1 bf16 hi/lo, 2 bf16.   ROPE: fuse rotation in epilogue.
// 128x128 tile, BK=32, 4 waves each 32(m) x 128(n): acc[2][8].
// Staging via global_load_lds (16B/lane), unpadded LDS [128][32].
// ---------------------------------------------------------------------------
template <int NTERM, int OMODE, int ROPE>
__global__ __launch_bounds__(256, 3)
void gemm_bt(const u16* __restrict__ Ah, const u16* __restrict__ Al,
             const u16* __restrict__ Bh, const u16* __restrict__ Bl,
             float* __restrict__ Cf, u16* __restrict__ Ch, u16* __restrict__ Cl,
             const float* __restrict__ cosT, const float* __restrict__ sinT,
             float scale, int M, int N, int K) {
  __shared__ u16 As[128 * 32];
  __shared__ u16 Bs[128 * 32];
  __shared__ u16 Asl[NTERM == 3 ? 128 * 32 : 8];
  __shared__ u16 Bsl[NTERM == 3 ? 128 * 32 : 8];
  const int bn = blockIdx.x, bm = blockIdx.y;
  const int t = threadIdx.x;
  const int w = t >> 6, lane = t & 63, quad = lane >> 4, lc = lane & 15;

  const f32x4 ZERO = {0.f, 0.f, 0.f, 0.f};
  f32x4 acc[2][8];
#pragma unroll
  for (int i = 0; i < 2; ++i)
#pragma unroll
    for (int j = 0; j < 8; ++j) acc[i][j] = ZERO;

  const int sr0 = (lane >> 2);
  const int sc0 = (lane & 3) * 8;
  const size_t arow0 = (size_t)bm * 128, brow0 = (size_t)bn * 128;

  for (int k0 = 0; k0 < K; k0 += 32) {
#pragma unroll
    for (int p = 0; p < 2; ++p) {
      const int ch = 2 * w + p;
      const int r = ch * 16 + sr0;
      const size_t ga = (arow0 + r) * (size_t)K + k0 + sc0;
      const size_t gb = (brow0 + r) * (size_t)K + k0 + sc0;
      const int ldso = ch * 512 + lane * 8;   // u16 index
      gld16(&Ah[ga], &As[ldso]);
      gld16(&Bh[gb], &Bs[ldso]);
      if constexpr (NTERM == 3) {
        gld16(&Al[ga], &Asl[ldso]);
        gld16(&Bl[gb], &Bsl[ldso]);
      }
    }
    __syncthreads();

    s16x8 ah[2], al[2];
#pragma unroll
    for (int i = 0; i < 2; ++i) {
      ah[i] = *(const s16x8*)&As[(32 * w + 16 * i + lc) * 32 + 8 * quad];
      if constexpr (NTERM == 3)
        al[i] = *(const s16x8*)&Asl[(32 * w + 16 * i + lc) * 32 + 8 * quad];
    }
#pragma unroll
    for (int j = 0; j < 8; ++j) {
      const s16x8 bh = *(const s16x8*)&Bs[(16 * j + lc) * 32 + 8 * quad];
      s16x8 bl;
      if constexpr (NTERM == 3)
        bl = *(const s16x8*)&Bsl[(16 * j + lc) * 32 + 8 * quad];
#pragma unroll
      for (int i = 0; i < 2; ++i) {
        acc[i][j] = MFMA(ah[i], bh, acc[i][j]);
        if constexpr (NTERM == 3) {
          acc[i][j] = MFMA(ah[i], bl, acc[i][j]);
          acc[i][j] = MFMA(al[i], bh, acc[i][j]);
        }
      }
    }
    __syncthreads();
  }

  // ---- epilogue ----
  if constexpr (ROPE) {
    // N-tile 128 == one head (bn*128 head-aligned). Pair cols d and d+64.
#pragma unroll
    for (int i = 0; i < 2; ++i)
#pragma unroll
      for (int r = 0; r < 4; ++r) {
        const int row = bm * 128 + 32 * w + 16 * i + 4 * quad + r;
        const int s = row & 2047;
#pragma unroll
        for (int j = 0; j < 4; ++j) {
          const int hd = 16 * j + lc;
          const float cs = cosT[s * 64 + hd], sn = sinT[s * 64 + hd];
          const float q1 = acc[i][j][r], q2 = acc[i][j + 4][r];
          const float o1 = (q1 * cs - q2 * sn) * scale;
          const float o2 = (q2 * cs + q1 * sn) * scale;
          const size_t p1 = (size_t)row * N + bn * 128 + hd;
          const u16 h1 = f2bf(o1);
          Ch[p1] = h1; Cl[p1] = f2bf(o1 - bf2f(h1));
          const u16 h2 = f2bf(o2);
          Ch[p1 + 64] = h2; Cl[p1 + 64] = f2bf(o2 - bf2f(h2));
        }
      }
  } else {
#pragma unroll
    for (int i = 0; i < 2; ++i)
#pragma unroll
      for (int j = 0; j < 8; ++j) {
        const int col = bn * 128 + 16 * j + lc;
#pragma unroll
        for (int r = 0; r < 4; ++r) {
          const int row = bm * 128 + 32 * w + 16 * i + 4 * quad + r;
          const float v = acc[i][j][r];
          if constexpr (OMODE == 0) {
            Cf[(size_t)row * N + col] = v;
          } else if constexpr (OMODE == 1) {
            const u16 hv = f2bf(v);
            Ch[(size_t)row * N + col] = hv;
            Cl[(size_t)row * N + col] = f2bf(v - bf2f(hv));
          } else {
            Ch[(size_t)row * N + col] = f2bf(v);
          }
        }
      }
  }
}

// ---------------------------------------------------------------------------
// Flash attention, causal, 32x32x16 swapped-operand MFMA, counted-vmcnt
// double-buffered pipeline.
// Q pre-scaled by sqrt(D) (folded into Q-GEMM epilogue).
// grid (8,16,2), 512 threads = 8 waves; block runs tasks (b=z,qt=x) then
// (b=1-z,qt=7-x): uniform 36 k-steps. QBLK=256: wave w owns q-rows
// [qt*256+32w, +32). KVBLK=64.
// LDS: 2 x {Kh 16K, Kl 16K, V 16K} dbuf (96KB) + 32KB O-transpose scratch.
// Staging: 6 global_load_lds(16B) per wave per step, source pre-swizzled
// (chunk ^= row&7) so linear LDS + XOR reads see correct data.
// Main loop: stage(t+1) -> s_waitcnt vmcnt(6) -> s_barrier -> compute(t)
// -> s_barrier. vmcnt never drained mid-loop.
// ---------------------------------------------------------------------------
__global__ __launch_bounds__(512, 2)
void attn(const u16* __restrict__ Qh, const u16* __restrict__ Ql,
          const u16* __restrict__ Kh, const u16* __restrict__ Kl,
          const u16* __restrict__ Vt, u16* __restrict__ Ctx) {
  __shared__ u16 SMEM[65536];               // 128 KB
  // buf p at p*24576: Kh [0,8192) Kl [8192,16384) V [16384,24576)
  // Os scratch at 49152 (16384 u16 = 32KB)

  const int t = threadIdx.x;
  const int w = t >> 6, lane = t & 63;
  const int l31 = lane & 31, hi = lane >> 5;
  const int swz = (l31 & 7) << 3;

  // ---- XCD-bijective remap: all 16 (x,z) blocks of a head on one XCD ----
  const int bid = (int)blockIdx.x + 8 * (int)blockIdx.y + 128 * (int)blockIdx.z;
  const int xcd = bid & 7, slot = bid >> 3;
  const int h = xcd * 2 + (slot >> 4);
  const int x = slot & 7, z = (slot >> 3) & 1;
  const int qtA = z ? x : 7 - x, bA = z;

  // ---- staging source offsets (u16 units), pre-swizzled ----
  const int offK0 = (8 * w + (lane >> 4)) * 2048 + (((lane & 15) ^ ((lane >> 4) & 7)) * 8);
  const int offK1 = (8 * w + 4 + (lane >> 4)) * 2048 + (((lane & 15) ^ ((4 + (lane >> 4)) & 7)) * 8);
  const int offV0 = (16 * w + (lane >> 3)) * 4096 + (((lane & 7) ^ ((lane >> 3) & 7)) * 8);
  const int offV1 = offV0 + 8 * 4096;

  auto stage = [&](const u16* gK, const u16* gKlo, const u16* gV, int kt, int bp) {
    u16* B = &SMEM[bp * 24576];
    const int ka = kt * 131072;   // kt*64*2048
    const int va = kt * 64;
    gld16(gK + ka + offK0, B + 1024 * w);
    gld16(gK + ka + offK1, B + 1024 * w + 512);
    gld16(gKlo + ka + offK0, B + 8192 + 1024 * w);
    gld16(gKlo + ka + offK1, B + 8192 + 1024 * w + 512);
    gld16(gV + va + offV0, B + 16384 + 1024 * w);
    gld16(gV + va + offV1, B + 16384 + 1024 * w + 512);
  };

  int bufph = 0;
  // prime: task A tile 0
  {
    const u16* gK0 = Kh + ((size_t)(bA * 2048)) * 2048 + h * 128;
    const u16* gL0 = Kl + ((size_t)(bA * 2048)) * 2048 + h * 128;
    const u16* gV0 = Vt + (size_t)(h * 128) * 4096 + bA * 2048;
    stage(gK0, gL0, gV0, 0, 0);
  }

  for (int task = 0; task < 2; ++task) {
    const int qt = task ? 7 - qtA : qtA;
    const int bb = task ? 1 - bA : bA;
    const u16* gK0 = Kh + ((size_t)(bb * 2048)) * 2048 + h * 128;
    const u16* gL0 = Kl + ((size_t)(bb * 2048)) * 2048 + h * 128;
    const u16* gV0 = Vt + (size_t)(h * 128) * 4096 + bb * 2048;
    // next task's pointers (for cross-task prefetch)
    const u16* nK0 = Kh + ((size_t)((1 - bb) * 2048)) * 2048 + h * 128;
    const u16* nL0 = Kl + ((size_t)((1 - bb) * 2048)) * 2048 + h * 128;
    const u16* nV0 = Vt + (size_t)(h * 128) * 4096 + (1 - bb) * 2048;

    const int qg = qt * 256 + 32 * w + l31;    // this lane's q row
    // ---- Q fragments ----
    s16x8 qfh[8], qfl[8];
    {
      const size_t qbase = ((size_t)(bb * 2048 + qg)) * 2048 + h * 128 + 8 * hi;
#pragma unroll
      for (int s = 0; s < 8; ++s) {
        qfh[s] = *(const s16x8*)&Qh[qbase + 16 * s];
        qfl[s] = *(const s16x8*)&Ql[qbase + 16 * s];
      }
    }

    float m_run = -3.0e38f, l_run = 0.f;
    f32x16 o[4];
#pragma unroll
    for (int d = 0; d < 4; ++d)
#pragma unroll
      for (int r = 0; r < 16; ++r) o[d][r] = 0.f;

    const int nt = 4 * qt + 4;
    for (int kt = 0; kt < nt; ++kt) {
      // ---- issue next stage (stays in flight across barriers) ----
      bool staged = true;
      if (kt + 1 < nt)      stage(gK0, gL0, gV0, kt + 1, bufph ^ 1);
      else if (task == 0)   stage(nK0, nL0, nV0, 0, bufph ^ 1);
      else                  staged = false;
      if (staged) asm volatile("s_waitcnt vmcnt(6)" ::: "memory");
      else        asm volatile("s_waitcnt vmcnt(0)" ::: "memory");
      __builtin_amdgcn_sched_barrier(0);
      __builtin_amdgcn_s_barrier();
      __builtin_amdgcn_sched_barrier(0);

      const bool active = (qt * 256 + 32 * w + 31) >= kt * 64;
      if (active) {
        const u16* Kb = &SMEM[bufph * 24576];
        const u16* Lb = Kb + 8192;
        const u16* Vb = Kb + 16384;
        // ---- S^T = K * Q^T (split precision, 3-term) ----
        f32x16 acc0, acc1;
#pragma unroll
        for (int r = 0; r < 16; ++r) { acc0[r] = 0.f; acc1[r] = 0.f; }
        __builtin_amdgcn_s_setprio(1);
#pragma unroll
        for (int s = 0; s < 8; ++s) {
          const int col = 16 * s + 8 * hi;
          const s16x8 k0h = *(const s16x8*)&Kb[((l31) * 128 + col) ^ swz];
          const s16x8 k0l = *(const s16x8*)&Lb[((l31) * 128 + col) ^ swz];
          acc0 = MFMA32(k0h, qfh[s], acc0);
          acc0 = MFMA32(k0l, qfh[s], acc0);
          acc0 = MFMA32(k0h, qfl[s], acc0);
          const s16x8 k1h = *(const s16x8*)&Kb[((32 + l31) * 128 + col) ^ swz];
          const s16x8 k1l = *(const s16x8*)&Lb[((32 + l31) * 128 + col) ^ swz];
          acc1 = MFMA32(k1h, qfh[s], acc1);
          acc1 = MFMA32(k1l, qfh[s], acc1);
          acc1 = MFMA32(k1h, qfl[s], acc1);
        }
        __builtin_amdgcn_s_setprio(0);

        // ---- causal mask + online softmax (lane-local) ----
        const int kb0 = kt * 64;
        const bool partial = (kt * 64 + 63) > (qt * 256 + 32 * w);
        float mx = -3.0e38f;
#pragma unroll
        for (int r = 0; r < 16; ++r) {
          const int koff = (r & 3) + 8 * (r >> 2) + 4 * hi;
          float v0 = acc0[r], v1 = acc1[r];
          if (partial) {
            if (kb0 + koff > qg) v0 = -3.0e38f;
            if (kb0 + 32 + koff > qg) v1 = -3.0e38f;
          }
          acc0[r] = v0; acc1[r] = v1;
          mx = fmaxf(mx, fmaxf(v0, v1));
        }
        mx = fmaxf(mx, __shfl_xor(mx, 32));    // combine k-halves (same q)
        const float mn = fmaxf(m_run, mx);
        const float al = __expf(m_run - mn);
        m_run = mn;
        float rs = 0.f;
#pragma unroll
        for (int r = 0; r < 16; ++r) {
          const float e0 = __expf(acc0[r] - mn);
          const float e1 = __expf(acc1[r] - mn);
          acc0[r] = e0; acc1[r] = e1;
          rs += e0 + e1;
        }
        rs += __shfl_xor(rs, 32);
        l_run = l_run * al + rs;
#pragma unroll
        for (int d = 0; d < 4; ++d)
#pragma unroll
          for (int r = 0; r < 16; ++r) o[d][r] *= al;

        // ---- pack P -> PV B-fragments (cvt_pk + permlane32_swap) ----
        s16x8 pb[4];
#pragma unroll
        for (int tt = 0; tt < 4; ++tt) {
          const int q2A = 2 * (tt & 1);
          float e0, e1, e2, e3, f0, f1, f2, f3;
          if (tt < 2) {
            e0 = acc0[4 * q2A + 0]; e1 = acc0[4 * q2A + 1];
            e2 = acc0[4 * q2A + 2]; e3 = acc0[4 * q2A + 3];
            f0 = acc0[4 * q2A + 4]; f1 = acc0[4 * q2A + 5];
            f2 = acc0[4 * q2A + 6]; f3 = acc0[4 * q2A + 7];
          } else {
            e0 = acc1[4 * q2A + 0]; e1 = acc1[4 * q2A + 1];
            e2 = acc1[4 * q2A + 2]; e3 = acc1[4 * q2A + 3];
            f0 = acc1[4 * q2A + 4]; f1 = acc1[4 * q2A + 5];
            f2 = acc1[4 * q2A + 6]; f3 = acc1[4 * q2A + 7];
          }
          unsigned a0 = cvtpk_bf16(e0, e1);
          unsigned a1 = cvtpk_bf16(e2, e3);
          unsigned b0 = cvtpk_bf16(f0, f1);
          unsigned b1 = cvtpk_bf16(f2, f3);
          asm volatile("v_permlane32_swap_b32 %0, %1" : "+v"(a0), "+v"(b0));
          asm volatile("v_permlane32_swap_b32 %0, %1" : "+v"(a1), "+v"(b1));
          union { unsigned u[4]; s16x8 v; } pk;
          pk.u[0] = a0; pk.u[1] = a1; pk.u[2] = b0; pk.u[3] = b1;
          pb[tt] = pk.v;
        }

        // ---- O^T += V^T * P ----
        __builtin_amdgcn_s_setprio(1);
#pragma unroll
        for (int d = 0; d < 4; ++d) {
#pragma unroll
          for (int tt = 0; tt < 4; ++tt) {
            const s16x8 va =
                *(const s16x8*)&Vb[((32 * d + l31) * 64 + 16 * tt + 8 * hi) ^ swz];
            o[d] = MFMA32(va, pb[tt], o[d]);
          }
        }
        __builtin_amdgcn_s_setprio(0);
      }
      __builtin_amdgcn_s_barrier();
      bufph ^= 1;
    }

    // ---- epilogue: normalize, transpose O^T -> O via 32KB scratch ----
    const float inv_l = 1.0f / l_run;
    u16* Os = &SMEM[49152];
    const int rl = (32 * w + l31) & 127;
#pragma unroll
    for (int half = 0; half < 2; ++half) {
      if ((w >> 2) == half) {
#pragma unroll
        for (int d = 0; d < 4; ++d)
#pragma unroll
          for (int r = 0; r < 16; r += 2) {
            const int dd = 32 * d + (r & 3) + 8 * (r >> 2) + 4 * hi;
            const unsigned pr = cvtpk_bf16(o[d][r] * inv_l, o[d][r + 1] * inv_l);
            *(unsigned*)&Os[(rl * 128 + dd) ^ ((rl & 7) << 3)] = pr;
          }
      }
      asm volatile("s_waitcnt lgkmcnt(0)" ::: "memory");
      __builtin_amdgcn_s_barrier();
      {
        const int rr = t >> 2, cb = (t & 3) * 32;
        const size_t ob =
            ((size_t)(bb * 2048 + qt * 256 + half * 128 + rr)) * 2048 + h * 128 + cb;
#pragma unroll
        for (int p = 0; p < 4; ++p)
          *(u16x8*)&Ctx[ob + 8 * p] =
              *(const u16x8*)&Os[(rr * 128 + cb + 8 * p) ^ ((rr & 7) << 3)];
      }
      asm volatile("s_waitcnt lgkmcnt(0)" ::: "memory");
      __builtin_amdgcn_s_barrier();
    }
  }
}

// ---------------------------------------------------------------------------
extern "C" void kernel_launch(void* const* d_in, const int* in_sizes, int n_in,
                              void* d_out, int out_size, void* d_ws, size_t ws_size,
                              hipStream_t stream) {
  const float* x  = (const float*)d_in[0];
  const float* Wq = (const float*)d_in[1];
  const float* Wk = (const float*)d_in[2];
  const float* Wv = (const float*)d_in[3];
  const float* Wo = (const float*)d_in[4];
  float* out = (float*)d_out;

  char* ws = (char*)d_ws;
  size_t off = 0;
  auto alloc = [&](size_t bytes) {
    char* p = ws + off;
    off += (bytes + 255) & ~(size_t)255;
    return p;
  };
  const size_t XE = (size_t)4096 * 2048;   // B*S x H elements
  const size_t WE = (size_t)2048 * 2048;

  u16* xh  = (u16*)alloc(XE * 2);
  u16* xl  = (u16*)alloc(XE * 2);
  u16* Wqh = (u16*)alloc(WE * 2);
  u16* Wql = (u16*)alloc(WE * 2);
  u16* Wkh = (u16*)alloc(WE * 2);
  u16* Wkl = (u16*)alloc(WE * 2);
  u16* Wvh = (u16*)alloc(WE * 2);
  u16* Woh = (u16*)alloc(WE * 2);
  u16* Qhb = (u16*)alloc(XE * 2);
  u16* Qlb = (u16*)alloc(XE * 2);
  u16* Khb = (u16*)alloc(XE * 2);
  u16* Klb = (u16*)alloc(XE * 2);
  u16* Vtb = (u16*)alloc(XE * 2);   // V^T: [2048 dims][4096 seq]
  u16* Ctxb = (u16*)alloc(XE * 2);
  float* cosT = (float*)alloc((size_t)2048 * 64 * 4);
  float* sinT = (float*)alloc((size_t)2048 * 64 * 4);
  (void)ws_size;  // requires ~170 MB of workspace
  (void)in_sizes; (void)n_in; (void)out_size;

  // 1) precision split + RoPE tables
  split_bf16<<<8192, 256, 0, stream>>>(x, xh, xl, (int)(XE / 4));
  split_bf16<<<4096, 256, 0, stream>>>(Wq, Wqh, Wql, (int)(WE / 4));
  split_bf16<<<4096, 256, 0, stream>>>(Wk, Wkh, Wkl, (int)(WE / 4));
  split_bf16<<<4096, 256, 0, stream>>>(Wv, Wvh, nullptr, (int)(WE / 4));
  split_bf16<<<4096, 256, 0, stream>>>(Wo, Woh, nullptr, (int)(WE / 4));
  rope_tab<<<512, 256, 0, stream>>>(cosT, sinT);

  // 2) projections: Q,K split-precision with fused RoPE; V^T directly
  gemm_bt<3, 1, 1><<<dim3(16, 32), 256, 0, stream>>>(
      xh, xl, Wqh, Wql, nullptr, Qhb, Qlb, cosT, sinT,
      11.313708498984760f, 4096, 2048, 2048);
  gemm_bt<3, 1, 1><<<dim3(16, 32), 256, 0, stream>>>(
      xh, xl, Wkh, Wkl, nullptr, Khb, Klb, cosT, sinT,
      1.0f, 4096, 2048, 2048);
  // V^T = Wv * x^T :  A=Wv (M=2048 dims), B=x (N=4096 seq)
  gemm_bt<1, 2, 0><<<dim3(32, 16), 256, 0, stream>>>(
      Wvh, nullptr, xh, nullptr, nullptr, Vtb, nullptr, nullptr, nullptr,
      1.0f, 2048, 4096, 2048);

  // 3) causal flash attention (counted-vmcnt dbuf pipeline)
  attn<<<dim3(8, 16, 2), 512, 0, stream>>>(Qhb, Qlb, Khb, Klb, Vtb, Ctxb);

  // 4) output projection -> fp32 d_out
  gemm_bt<1, 0, 0><<<dim3(16, 32), 256, 0, stream>>>(
      Ctxb, nullptr, Woh, nullptr, out, nullptr, nullptr, nullptr, nullptr,
      1.0f, 4096, 2048, 2048);
}

// Round 4
// 570.480 us; speedup vs baseline: 1.1770x; 1.1286x over previous
//
#include <hip/hip_runtime.h>
#include <cmath>

// ============================================================================
// AutoregressiveGroupQuerySelfAttention  (B=2, S=2048, H=2048, nH=16, D=128)
//
// Round 8: de-duplicate the attn task map (R7 computed every task TWICE:
// (x,z=0) and (x,z=1) covered identical (b,qt) pairs -> 2x work, flat time).
//  - QBLK=128: 512 tasks total, paired (qt, 15-qt) -> 256 blocks x uniform
//    34 steps, every task unique, all 256 CUs busy.
//  - 8 waves = 4 q-slices x 2 k-halves: wave w owns q rows [qt*128+32*(w>>1))
//    and k-half (w&1) of each 64-wide tile. Private (m,l,O) per wave; one
//    f32 LDS merge per task in the epilogue (no per-step cross-wave traffic).
//  - Counted-vmcnt dbuf pipeline, pre-swizzled global_load_lds staging,
//    cross-task prefetch, 32x32x16 swapped-operand MFMA: kept from R7.
//  - GEMM path unchanged.
// ============================================================================

typedef unsigned short u16;
typedef __attribute__((ext_vector_type(4))) float  f32x4;
typedef __attribute__((ext_vector_type(16))) float f32x16;
typedef __attribute__((ext_vector_type(4))) float  float4v;
typedef __attribute__((ext_vector_type(4))) unsigned short u16x4;
typedef __attribute__((ext_vector_type(8))) unsigned short u16x8;
typedef __attribute__((ext_vector_type(8))) short s16x8;

__device__ __forceinline__ u16 f2bf(float f) {
  unsigned u = __float_as_uint(f);
  u += 0x7FFFu + ((u >> 16) & 1u);            // RNE; inputs are finite
  return (u16)(u >> 16);
}
__device__ __forceinline__ float bf2f(u16 h) {
  return __uint_as_float(((unsigned)h) << 16);
}
__device__ __forceinline__ f32x4 MFMA(s16x8 a, s16x8 b, f32x4 c) {
  return __builtin_amdgcn_mfma_f32_16x16x32_bf16(a, b, c, 0, 0, 0);
}
__device__ __forceinline__ f32x16 MFMA32(s16x8 a, s16x8 b, f32x16 c) {
  return __builtin_amdgcn_mfma_f32_32x32x16_bf16(a, b, c, 0, 0, 0);
}
__device__ __forceinline__ unsigned cvtpk_bf16(float lo, float hi) {
  unsigned r;
  asm("v_cvt_pk_bf16_f32 %0, %1, %2" : "=v"(r) : "v"(lo), "v"(hi));
  return r;
}
// async global->LDS, 16B per lane; LDS dest = wave-uniform base + lane*16
__device__ __forceinline__ void gld16(const void* g, void* s) {
  __builtin_amdgcn_global_load_lds(
      (const __attribute__((address_space(1))) void*)g,
      (__attribute__((address_space(3))) void*)s, 16, 0, 0);
}

// ---------------------------------------------------------------------------
// fp32 -> bf16 hi (+ optional lo residual).  n4 = element count / 4.
// ---------------------------------------------------------------------------
__global__ void split_bf16(const float* __restrict__ src, u16* __restrict__ hi,
                           u16* __restrict__ lo, int n4) {
  int i = blockIdx.x * 256 + threadIdx.x;
  if (i >= n4) return;
  float4v v = ((const float4v*)src)[i];
  u16x4 hv, lv;
#pragma unroll
  for (int j = 0; j < 4; ++j) {
    float f = v[j];
    u16 h = f2bf(f);
    hv[j] = h;
    lv[j] = f2bf(f - bf2f(h));
  }
  ((u16x4*)hi)[i] = hv;
  if (lo) ((u16x4*)lo)[i] = lv;
}

// ---------------------------------------------------------------------------
// RoPE tables in fp64.
// ---------------------------------------------------------------------------
__global__ void rope_tab(float* __restrict__ cosT, float* __restrict__ sinT) {
  int idx = blockIdx.x * 256 + threadIdx.x;   // 2048*64
  int i = idx & 63, s = idx >> 6;
  double invf = pow(10000.0, -(double)i / 64.0);
  double ang = (double)s * invf;
  cosT[idx] = (float)cos(ang);
  sinT[idx] = (float)sin(ang);
}

// ---------------------------------------------------------------------------
// GEMM  C(MxN) = A(MxK) * B(NxK)^T, bf16 inputs, fp32 accumulate.
// NTERM==3: split precision (hh+hl+lh).
// OMODE: 0 fp32, 1 bf16 hi/lo, 2 bf16.   ROPE: fuse rotation in epilogue.
// 128x128 tile, BK=32, 4 waves each 32(m) x 128(n): acc[2][8].
// Staging via global_load_lds (16B/lane), unpadded LDS [128][32].
// ---------------------------------------------------------------------------
template <int NTERM, int OMODE, int ROPE>
__global__ __launch_bounds__(256, 3)
void gemm_bt(const u16* __restrict__ Ah, const u16* __restrict__ Al,
             const u16* __restrict__ Bh, const u16* __restrict__ Bl,
             float* __restrict__ Cf, u16* __restrict__ Ch, u16* __restrict__ Cl,
             const float* __restrict__ cosT, const float* __restrict__ sinT,
             float scale, int M, int N, int K) {
  __shared__ u16 As[128 * 32];
  __shared__ u16 Bs[128 * 32];
  __shared__ u16 Asl[NTERM == 3 ? 128 * 32 : 8];
  __shared__ u16 Bsl[NTERM == 3 ? 128 * 32 : 8];
  const int bn = blockIdx.x, bm = blockIdx.y;
  const int t = threadIdx.x;
  const int w = t >> 6, lane = t & 63, quad = lane >> 4, lc = lane & 15;

  const f32x4 ZERO = {0.f, 0.f, 0.f, 0.f};
  f32x4 acc[2][8];
#pragma unroll
  for (int i = 0; i < 2; ++i)
#pragma unroll
    for (int j = 0; j < 8; ++j) acc[i][j] = ZERO;

  const int sr0 = (lane >> 2);
  const int sc0 = (lane & 3) * 8;
  const size_t arow0 = (size_t)bm * 128, brow0 = (size_t)bn * 128;

  for (int k0 = 0; k0 < K; k0 += 32) {
#pragma unroll
    for (int p = 0; p < 2; ++p) {
      const int ch = 2 * w + p;
      const int r = ch * 16 + sr0;
      const size_t ga = (arow0 + r) * (size_t)K + k0 + sc0;
      const size_t gb = (brow0 + r) * (size_t)K + k0 + sc0;
      const int ldso = ch * 512 + lane * 8;   // u16 index
      gld16(&Ah[ga], &As[ldso]);
      gld16(&Bh[gb], &Bs[ldso]);
      if constexpr (NTERM == 3) {
        gld16(&Al[ga], &Asl[ldso]);
        gld16(&Bl[gb], &Bsl[ldso]);
      }
    }
    __syncthreads();

    s16x8 ah[2], al[2];
#pragma unroll
    for (int i = 0; i < 2; ++i) {
      ah[i] = *(const s16x8*)&As[(32 * w + 16 * i + lc) * 32 + 8 * quad];
      if constexpr (NTERM == 3)
        al[i] = *(const s16x8*)&Asl[(32 * w + 16 * i + lc) * 32 + 8 * quad];
    }
#pragma unroll
    for (int j = 0; j < 8; ++j) {
      const s16x8 bh = *(const s16x8*)&Bs[(16 * j + lc) * 32 + 8 * quad];
      s16x8 bl;
      if constexpr (NTERM == 3)
        bl = *(const s16x8*)&Bsl[(16 * j + lc) * 32 + 8 * quad];
#pragma unroll
      for (int i = 0; i < 2; ++i) {
        acc[i][j] = MFMA(ah[i], bh, acc[i][j]);
        if constexpr (NTERM == 3) {
          acc[i][j] = MFMA(ah[i], bl, acc[i][j]);
          acc[i][j] = MFMA(al[i], bh, acc[i][j]);
        }
      }
    }
    __syncthreads();
  }

  // ---- epilogue ----
  if constexpr (ROPE) {
    // N-tile 128 == one head (bn*128 head-aligned). Pair cols d and d+64.
#pragma unroll
    for (int i = 0; i < 2; ++i)
#pragma unroll
      for (int r = 0; r < 4; ++r) {
        const int row = bm * 128 + 32 * w + 16 * i + 4 * quad + r;
        const int s = row & 2047;
#pragma unroll
        for (int j = 0; j < 4; ++j) {
          const int hd = 16 * j + lc;
          const float cs = cosT[s * 64 + hd], sn = sinT[s * 64 + hd];
          const float q1 = acc[i][j][r], q2 = acc[i][j + 4][r];
          const float o1 = (q1 * cs - q2 * sn) * scale;
          const float o2 = (q2 * cs + q1 * sn) * scale;
          const size_t p1 = (size_t)row * N + bn * 128 + hd;
          const u16 h1 = f2bf(o1);
          Ch[p1] = h1; Cl[p1] = f2bf(o1 - bf2f(h1));
          const u16 h2 = f2bf(o2);
          Ch[p1 + 64] = h2; Cl[p1 + 64] = f2bf(o2 - bf2f(h2));
        }
      }
  } else {
#pragma unroll
    for (int i = 0; i < 2; ++i)
#pragma unroll
      for (int j = 0; j < 8; ++j) {
        const int col = bn * 128 + 16 * j + lc;
#pragma unroll
        for (int r = 0; r < 4; ++r) {
          const int row = bm * 128 + 32 * w + 16 * i + 4 * quad + r;
          const float v = acc[i][j][r];
          if constexpr (OMODE == 0) {
            Cf[(size_t)row * N + col] = v;
          } else if constexpr (OMODE == 1) {
            const u16 hv = f2bf(v);
            Ch[(size_t)row * N + col] = hv;
            Cl[(size_t)row * N + col] = f2bf(v - bf2f(hv));
          } else {
            Ch[(size_t)row * N + col] = f2bf(v);
          }
        }
      }
  }
}

// ---------------------------------------------------------------------------
// Flash attention, causal, 32x32x16 swapped-operand MFMA, counted-vmcnt
// double-buffered pipeline, QBLK=128, k-split wave pairs.
// grid (8,16,2) remapped: 256 blocks, each runs tasks (bA,qtA) then
// (1-bA, 15-qtA): uniform 34 k-steps, every (h,b,qt) task computed once.
// 512 threads = 8 waves: wave w -> q-slice j=w>>1 (rows qt*128+32j..+31),
// k-half kh=w&1 (cols 32kh..32kh+31 of each 64-wide K tile).
// Per wave private (m,l,O) over its k-half; merged once per task via f32
// LDS exchange in the epilogue.
// LDS: 2 x {Kh 16K, Kl 16K, V 16K} dbuf (96KB) + 32KB scratch = 128KB.
// Main loop: stage(t+1) -> s_waitcnt vmcnt(6) -> s_barrier -> compute(t)
// -> s_barrier. vmcnt never drained mid-loop; cross-task prefetch.
// ---------------------------------------------------------------------------
__global__ __launch_bounds__(512, 2)
void attn(const u16* __restrict__ Qh, const u16* __restrict__ Ql,
          const u16* __restrict__ Kh, const u16* __restrict__ Kl,
          const u16* __restrict__ Vt, u16* __restrict__ Ctx) {
  __shared__ u16 SMEM[65536];               // 128 KB
  // buf p at u16 p*24576: Kh [0,8192) Kl [8192,16384) V [16384,24576)
  // scratch at u16 49152 (32 KB): m/l exchange, then O exchange, then Os

  const int t = threadIdx.x;
  const int w = t >> 6, lane = t & 63;
  const int l31 = lane & 31, hi = lane >> 5;
  const int swz = (l31 & 7) << 3;
  const int j = w >> 1, kh = w & 1;         // q-slice, k-half

  // ---- XCD remap: 16 blocks of a head on one XCD; unique task pairs ----
  const int bid = (int)blockIdx.x + 8 * (int)blockIdx.y + 128 * (int)blockIdx.z;
  const int xcd = bid & 7, slot = bid >> 3;          // slot 0..31
  const int h = xcd * 2 + (slot >> 4);
  const int rem = slot & 15;
  const int qtA = rem & 7, bA = rem >> 3;            // task A: (bA, qtA)
  // task B: (1-bA, 15-qtA).  Coverage: qt<=7 via A, qt>=8 via B, each once.

  // ---- staging source offsets (u16 units), pre-swizzled ----
  const int offK0 = (8 * w + (lane >> 4)) * 2048 + (((lane & 15) ^ ((lane >> 4) & 7)) * 8);
  const int offK1 = (8 * w + 4 + (lane >> 4)) * 2048 + (((lane & 15) ^ ((4 + (lane >> 4)) & 7)) * 8);
  const int offV0 = (16 * w + (lane >> 3)) * 4096 + (((lane & 7) ^ ((lane >> 3) & 7)) * 8);
  const int offV1 = offV0 + 8 * 4096;

  auto stage = [&](const u16* gK, const u16* gKlo, const u16* gV, int kt, int bp) {
    u16* B = &SMEM[bp * 24576];
    const int ka = kt * 131072;   // kt*64*2048
    const int va = kt * 64;
    gld16(gK + ka + offK0, B + 1024 * w);
    gld16(gK + ka + offK1, B + 1024 * w + 512);
    gld16(gKlo + ka + offK0, B + 8192 + 1024 * w);
    gld16(gKlo + ka + offK1, B + 8192 + 1024 * w + 512);
    gld16(gV + va + offV0, B + 16384 + 1024 * w);
    gld16(gV + va + offV1, B + 16384 + 1024 * w + 512);
  };

  int bufph = 0;
  // prime: task A tile 0
  {
    const u16* gK0 = Kh + ((size_t)(bA * 2048)) * 2048 + h * 128;
    const u16* gL0 = Kl + ((size_t)(bA * 2048)) * 2048 + h * 128;
    const u16* gV0 = Vt + (size_t)(h * 128) * 4096 + bA * 2048;
    stage(gK0, gL0, gV0, 0, 0);
  }

  for (int task = 0; task < 2; ++task) {
    const int qt = task ? 15 - qtA : qtA;
    const int bb = task ? 1 - bA : bA;
    const u16* gK0 = Kh + ((size_t)(bb * 2048)) * 2048 + h * 128;
    const u16* gL0 = Kl + ((size_t)(bb * 2048)) * 2048 + h * 128;
    const u16* gV0 = Vt + (size_t)(h * 128) * 4096 + bb * 2048;
    // next task's pointers (for cross-task prefetch)
    const int nb = 1 - bb;
    const u16* nK0 = Kh + ((size_t)(nb * 2048)) * 2048 + h * 128;
    const u16* nL0 = Kl + ((size_t)(nb * 2048)) * 2048 + h * 128;
    const u16* nV0 = Vt + (size_t)(h * 128) * 4096 + nb * 2048;

    const int q0 = qt * 128 + 32 * j;          // wave's first q row
    const int qg = q0 + l31;                   // this lane's q row
    // ---- Q fragments ----
    s16x8 qfh[8], qfl[8];
    {
      const size_t qbase = ((size_t)(bb * 2048 + qg)) * 2048 + h * 128 + 8 * hi;
#pragma unroll
      for (int s = 0; s < 8; ++s) {
        qfh[s] = *(const s16x8*)&Qh[qbase + 16 * s];
        qfl[s] = *(const s16x8*)&Ql[qbase + 16 * s];
      }
    }

    float m_run = -3.0e38f, l_run = 0.f;
    f32x16 o[4];
#pragma unroll
    for (int d = 0; d < 4; ++d)
#pragma unroll
      for (int r = 0; r < 16; ++r) o[d][r] = 0.f;

    const int nt = 2 * qt + 2;
    for (int kt = 0; kt < nt; ++kt) {
      // ---- issue next stage (stays in flight across barriers) ----
      bool staged = true;
      if (kt + 1 < nt)      stage(gK0, gL0, gV0, kt + 1, bufph ^ 1);
      else if (task == 0)   stage(nK0, nL0, nV0, 0, bufph ^ 1);
      else                  staged = false;
      if (staged) asm volatile("s_waitcnt vmcnt(6)" ::: "memory");
      else        asm volatile("s_waitcnt vmcnt(0)" ::: "memory");
      __builtin_amdgcn_sched_barrier(0);
      __builtin_amdgcn_s_barrier();
      __builtin_amdgcn_sched_barrier(0);

      const int kb0 = kt * 64 + 32 * kh;       // wave's k-half base
      const bool active = (q0 + 31) >= kb0;
      if (active) {
        const u16* Kb = &SMEM[bufph * 24576];
        const u16* Lb = Kb + 8192;
        const u16* Vb = Kb + 16384;
        // ---- S^T (wave's 32k x 32q block), split precision 3-term ----
        f32x16 acc;
#pragma unroll
        for (int r = 0; r < 16; ++r) acc[r] = 0.f;
        __builtin_amdgcn_s_setprio(1);
#pragma unroll
        for (int s = 0; s < 8; ++s) {
          const int col = 16 * s + 8 * hi;
          const s16x8 kha = *(const s16x8*)&Kb[((32 * kh + l31) * 128 + col) ^ swz];
          const s16x8 kla = *(const s16x8*)&Lb[((32 * kh + l31) * 128 + col) ^ swz];
          acc = MFMA32(kha, qfh[s], acc);
          acc = MFMA32(kla, qfh[s], acc);
          acc = MFMA32(kha, qfl[s], acc);
        }
        __builtin_amdgcn_s_setprio(0);

        // ---- causal mask + online softmax (lane-local, wave-private) ----
        const bool partial = (kb0 + 31) > q0;
        float mx = -3.0e38f;
#pragma unroll
        for (int r = 0; r < 16; ++r) {
          const int koff = (r & 3) + 8 * (r >> 2) + 4 * hi;
          float v = acc[r];
          if (partial && (kb0 + koff > qg)) v = -3.0e38f;
          acc[r] = v;
          mx = fmaxf(mx, v);
        }
        mx = fmaxf(mx, __shfl_xor(mx, 32));    // combine hi halves (same q)
        const float mn = fmaxf(m_run, mx);
        const float al = __expf(m_run - mn);
        m_run = mn;
        float rs = 0.f;
#pragma unroll
        for (int r = 0; r < 16; ++r) {
          const float e = __expf(acc[r] - mn);
          acc[r] = e;
          rs += e;
        }
        rs += __shfl_xor(rs, 32);
        l_run = l_run * al + rs;
#pragma unroll
        for (int d = 0; d < 4; ++d)
#pragma unroll
          for (int r = 0; r < 16; ++r) o[d][r] *= al;

        // ---- pack P -> PV B-fragments (cvt_pk + permlane32_swap) ----
        s16x8 pb[2];
#pragma unroll
        for (int tt = 0; tt < 2; ++tt) {
          const int q2A = 2 * tt;
          const float e0 = acc[4 * q2A + 0], e1 = acc[4 * q2A + 1];
          const float e2 = acc[4 * q2A + 2], e3 = acc[4 * q2A + 3];
          const float f0 = acc[4 * q2A + 4], f1 = acc[4 * q2A + 5];
          const float f2 = acc[4 * q2A + 6], f3 = acc[4 * q2A + 7];
          unsigned a0 = cvtpk_bf16(e0, e1);
          unsigned a1 = cvtpk_bf16(e2, e3);
          unsigned b0 = cvtpk_bf16(f0, f1);
          unsigned b1 = cvtpk_bf16(f2, f3);
          asm volatile("v_permlane32_swap_b32 %0, %1" : "+v"(a0), "+v"(b0));
          asm volatile("v_permlane32_swap_b32 %0, %1" : "+v"(a1), "+v"(b1));
          union { unsigned u[4]; s16x8 v; } pk;
          pk.u[0] = a0; pk.u[1] = a1; pk.u[2] = b0; pk.u[3] = b1;
          pb[tt] = pk.v;
        }

        // ---- O^T += V^T[:, wave's k-half] * P ----
        __builtin_amdgcn_s_setprio(1);
#pragma unroll
        for (int d = 0; d < 4; ++d) {
#pragma unroll
          for (int tt = 0; tt < 2; ++tt) {
            const s16x8 va = *(const s16x8*)
                &Vb[((32 * d + l31) * 64 + 16 * (2 * kh + tt) + 8 * hi) ^ swz];
            o[d] = MFMA32(va, pb[tt], o[d]);
          }
        }
        __builtin_amdgcn_s_setprio(0);
      }
      __builtin_amdgcn_s_barrier();
      bufph ^= 1;
    }

    // ======== epilogue: merge k-half wave pairs, normalize, store ========
    float* Sf = (float*)&SMEM[49152];          // 32KB scratch as f32[8192]
    // (1) m/l exchange
    Sf[w * 64 + lane] = m_run;
    Sf[512 + w * 64 + lane] = l_run;
    asm volatile("s_waitcnt lgkmcnt(0)" ::: "memory");
    __builtin_amdgcn_s_barrier();
    const float mOth = Sf[(w ^ 1) * 64 + lane];
    const float lOth = Sf[512 + (w ^ 1) * 64 + lane];
    const float mC = fmaxf(m_run, mOth);
    const float eS = __expf(m_run - mC);
    const float eO = __expf(mOth - mC);
    const float lC = eS * l_run + eO * lOth;
    // scale own partial O (odd waves hand over pre-scaled)
#pragma unroll
    for (int d = 0; d < 4; ++d)
#pragma unroll
      for (int r = 0; r < 16; ++r) o[d][r] *= eS;
    __builtin_amdgcn_s_barrier();              // m/l reads done before reuse
    // (2) O exchange: odd wave -> even wave, 2 rounds of 32KB
#pragma unroll
    for (int round = 0; round < 2; ++round) {
      if ((w >> 2) == round && kh == 1) {
        const int sl = j & 1;
#pragma unroll
        for (int d = 0; d < 4; ++d)
#pragma unroll
          for (int rr = 0; rr < 4; ++rr) {
            float4v c;
            c[0] = o[d][4 * rr + 0]; c[1] = o[d][4 * rr + 1];
            c[2] = o[d][4 * rr + 2]; c[3] = o[d][4 * rr + 3];
            const int cidx = 4 * (d * 4 + rr);
            *(float4v*)&Sf[sl * 4096 + ((lane * 64 + cidx) ^ ((lane & 7) << 2))] = c;
          }
      }
      asm volatile("s_waitcnt lgkmcnt(0)" ::: "memory");
      __builtin_amdgcn_s_barrier();
      if ((w >> 2) == round && kh == 0) {
        const int sl = j & 1;
#pragma unroll
        for (int d = 0; d < 4; ++d)
#pragma unroll
          for (int rr = 0; rr < 4; ++rr) {
            const int cidx = 4 * (d * 4 + rr);
            const float4v c =
                *(const float4v*)&Sf[sl * 4096 + ((lane * 64 + cidx) ^ ((lane & 7) << 2))];
            o[d][4 * rr + 0] += c[0]; o[d][4 * rr + 1] += c[1];
            o[d][4 * rr + 2] += c[2]; o[d][4 * rr + 3] += c[3];
          }
      }
      __builtin_amdgcn_s_barrier();
    }
    // (3) even waves: normalize + transposed bf16 write to Os
    u16* Os = &SMEM[49152];                    // [128][128] u16, swizzled
    if (kh == 0) {
      const float inv_l = 1.0f / lC;
      const int rl = 32 * j + l31;
#pragma unroll
      for (int d = 0; d < 4; ++d)
#pragma unroll
        for (int r = 0; r < 16; r += 2) {
          const int dd = 32 * d + (r & 3) + 8 * (r >> 2) + 4 * hi;
          const unsigned pr = cvtpk_bf16(o[d][r] * inv_l, o[d][r + 1] * inv_l);
          *(unsigned*)&Os[(rl * 128 + dd) ^ ((rl & 7) << 3)] = pr;
        }
    }
    asm volatile("s_waitcnt lgkmcnt(0)" ::: "memory");
    __builtin_amdgcn_s_barrier();
    // (4) coalesced store, all 8 waves
    {
      const int rr = t >> 2, cb = (t & 3) * 32;
      const size_t ob =
          ((size_t)(bb * 2048 + qt * 128 + rr)) * 2048 + h * 128 + cb;
#pragma unroll
      for (int p = 0; p < 4; ++p)
        *(u16x8*)&Ctx[ob + 8 * p] =
            *(const u16x8*)&Os[(rr * 128 + cb + 8 * p) ^ ((rr & 7) << 3)];
    }
    asm volatile("s_waitcnt lgkmcnt(0)" ::: "memory");
    __builtin_amdgcn_s_barrier();
  }
}

// ---------------------------------------------------------------------------
extern "C" void kernel_launch(void* const* d_in, const int* in_sizes, int n_in,
                              void* d_out, int out_size, void* d_ws, size_t ws_size,
                              hipStream_t stream) {
  const float* x  = (const float*)d_in[0];
  const float* Wq = (const float*)d_in[1];
  const float* Wk = (const float*)d_in[2];
  const float* Wv = (const float*)d_in[3];
  const float* Wo = (const float*)d_in[4];
  float* out = (float*)d_out;

  char* ws = (char*)d_ws;
  size_t off = 0;
  auto alloc = [&](size_t bytes) {
    char* p = ws + off;
    off += (bytes + 255) & ~(size_t)255;
    return p;
  };
  const size_t XE = (size_t)4096 * 2048;   // B*S x H elements
  const size_t WE = (size_t)2048 * 2048;

  u16* xh  = (u16*)alloc(XE * 2);
  u16* xl  = (u16*)alloc(XE * 2);
  u16* Wqh = (u16*)alloc(WE * 2);
  u16* Wql = (u16*)alloc(WE * 2);
  u16* Wkh = (u16*)alloc(WE * 2);
  u16* Wkl = (u16*)alloc(WE * 2);
  u16* Wvh = (u16*)alloc(WE * 2);
  u16* Woh = (u16*)alloc(WE * 2);
  u16* Qhb = (u16*)alloc(XE * 2);
  u16* Qlb = (u16*)alloc(XE * 2);
  u16* Khb = (u16*)alloc(XE * 2);
  u16* Klb = (u16*)alloc(XE * 2);
  u16* Vtb = (u16*)alloc(XE * 2);   // V^T: [2048 dims][4096 seq]
  u16* Ctxb = (u16*)alloc(XE * 2);
  float* cosT = (float*)alloc((size_t)2048 * 64 * 4);
  float* sinT = (float*)alloc((size_t)2048 * 64 * 4);
  (void)ws_size;  // requires ~170 MB of workspace
  (void)in_sizes; (void)n_in; (void)out_size;

  // 1) precision split + RoPE tables
  split_bf16<<<8192, 256, 0, stream>>>(x, xh, xl, (int)(XE / 4));
  split_bf16<<<4096, 256, 0, stream>>>(Wq, Wqh, Wql, (int)(WE / 4));
  split_bf16<<<4096, 256, 0, stream>>>(Wk, Wkh, Wkl, (int)(WE / 4));
  split_bf16<<<4096, 256, 0, stream>>>(Wv, Wvh, nullptr, (int)(WE / 4));
  split_bf16<<<4096, 256, 0, stream>>>(Wo, Woh, nullptr, (int)(WE / 4));
  rope_tab<<<512, 256, 0, stream>>>(cosT, sinT);

  // 2) projections: Q,K split-precision with fused RoPE; V^T directly
  gemm_bt<3, 1, 1><<<dim3(16, 32), 256, 0, stream>>>(
      xh, xl, Wqh, Wql, nullptr, Qhb, Qlb, cosT, sinT,
      11.313708498984760f, 4096, 2048, 2048);
  gemm_bt<3, 1, 1><<<dim3(16, 32), 256, 0, stream>>>(
      xh, xl, Wkh, Wkl, nullptr, Khb, Klb, cosT, sinT,
      1.0f, 4096, 2048, 2048);
  // V^T = Wv * x^T :  A=Wv (M=2048 dims), B=x (N=4096 seq)
  gemm_bt<1, 2, 0><<<dim3(32, 16), 256, 0, stream>>>(
      Wvh, nullptr, xh, nullptr, nullptr, Vtb, nullptr, nullptr, nullptr,
      1.0f, 2048, 4096, 2048);

  // 3) causal flash attention (de-duped task map, k-split wave pairs)
  attn<<<dim3(8, 16, 2), 512, 0, stream>>>(Qhb, Qlb, Khb, Klb, Vtb, Ctxb);

  // 4) output projection -> fp32 d_out
  gemm_bt<1, 0, 0><<<dim3(16, 32), 256, 0, stream>>>(
      Ctxb, nullptr, Woh, nullptr, out, nullptr, nullptr, nullptr, nullptr,
      1.0f, 4096, 2048, 2048);
}

// Round 5
// 548.887 us; speedup vs baseline: 1.2233x; 1.0393x over previous
//
#include <hip/hip_runtime.h>
#include <cmath>

// ============================================================================
// AutoregressiveGroupQuerySelfAttention  (B=2, S=2048, H=2048, nH=16, D=128)
//
// Round 9: GEMMs rewritten as gemm8 — 256x128 tile, BK=32, 8 waves (4Mx2N),
// counted-vmcnt double-buffered pipeline (the structure that lifted attn
// MfmaUtil 14->30% in R7/R8). Old 128^2 gemm_bt was at its ~900TF structural
// ceiling (852 TF effective, MfmaUtil 36%).
//  - 32x32x16 MFMA frags; per-wave 64x64 output (LDS-traffic-optimal 4Mx2N).
//  - Staging via global_load_lds, global source pre-swizzled with involution
//    q ^= (q>>3)&7 on 16B chunks (8 consecutive rows -> 8 distinct bank
//    groups; read side applies the same XOR). LDS dest stays linear.
//  - Loop: stage(t+1) -> vmcnt(6|3) -> s_barrier -> ds_read+MFMA(setprio)
//    -> s_barrier. vmcnt never drained mid-loop.
//  - ROPE pairing: n-wave wn owns cols {32wn..+32} U {64+32wn..+32}, so
//    (d, d+64) sit in the same lane's two n-frags -> elementwise rotation.
//  - attn kernel unchanged from R8 (de-duped task map, k-split wave pairs).
// ============================================================================

typedef unsigned short u16;
typedef __attribute__((ext_vector_type(4))) float  f32x4;
typedef __attribute__((ext_vector_type(16))) float f32x16;
typedef __attribute__((ext_vector_type(4))) float  float4v;
typedef __attribute__((ext_vector_type(4))) unsigned short u16x4;
typedef __attribute__((ext_vector_type(8))) unsigned short u16x8;
typedef __attribute__((ext_vector_type(8))) short s16x8;

__device__ __forceinline__ u16 f2bf(float f) {
  unsigned u = __float_as_uint(f);
  u += 0x7FFFu + ((u >> 16) & 1u);            // RNE; inputs are finite
  return (u16)(u >> 16);
}
__device__ __forceinline__ float bf2f(u16 h) {
  return __uint_as_float(((unsigned)h) << 16);
}
__device__ __forceinline__ f32x16 MFMA32(s16x8 a, s16x8 b, f32x16 c) {
  return __builtin_amdgcn_mfma_f32_32x32x16_bf16(a, b, c, 0, 0, 0);
}
__device__ __forceinline__ unsigned cvtpk_bf16(float lo, float hi) {
  unsigned r;
  asm("v_cvt_pk_bf16_f32 %0, %1, %2" : "=v"(r) : "v"(lo), "v"(hi));
  return r;
}
// async global->LDS, 16B per lane; LDS dest = wave-uniform base + lane*16
__device__ __forceinline__ void gld16(const void* g, void* s) {
  __builtin_amdgcn_global_load_lds(
      (const __attribute__((address_space(1))) void*)g,
      (__attribute__((address_space(3))) void*)s, 16, 0, 0);
}

// ---------------------------------------------------------------------------
// fp32 -> bf16 hi (+ optional lo residual).  n4 = element count / 4.
// ---------------------------------------------------------------------------
__global__ void split_bf16(const float* __restrict__ src, u16* __restrict__ hi,
                           u16* __restrict__ lo, int n4) {
  int i = blockIdx.x * 256 + threadIdx.x;
  if (i >= n4) return;
  float4v v = ((const float4v*)src)[i];
  u16x4 hv, lv;
#pragma unroll
  for (int j = 0; j < 4; ++j) {
    float f = v[j];
    u16 h = f2bf(f);
    hv[j] = h;
    lv[j] = f2bf(f - bf2f(h));
  }
  ((u16x4*)hi)[i] = hv;
  if (lo) ((u16x4*)lo)[i] = lv;
}

// ---------------------------------------------------------------------------
// RoPE tables in fp64.
// ---------------------------------------------------------------------------
__global__ void rope_tab(float* __restrict__ cosT, float* __restrict__ sinT) {
  int idx = blockIdx.x * 256 + threadIdx.x;   // 2048*64
  int i = idx & 63, s = idx >> 6;
  double invf = pow(10000.0, -(double)i / 64.0);
  double ang = (double)s * invf;
  cosT[idx] = (float)cos(ang);
  sinT[idx] = (float)sin(ang);
}

// ---------------------------------------------------------------------------
// gemm8:  C(MxN) = A(MxK) * B(NxK)^T, bf16 inputs, fp32 accumulate.
// NTERM==3: split precision (hh+hl+lh).
// OMODE: 0 fp32, 1 bf16 hi/lo, 2 bf16.   ROPE: fuse rotation in epilogue.
// 256x128 tile, BK=32, 512 thr = 8 waves (wm=w>>1 in 0..3, wn=w&1).
// Per-wave output 64 rows x 64 cols, cols = {32wn..+32} U {64+32wn..+32}.
// LDS per buffer (u16): Ah[8192] (+Al[8192]) Bh[4096] (+Bl[4096]);
// double-buffered: 96KB (NTERM=3) / 48KB (NTERM=1).
// Swizzle: 16B-chunk involution q ^= (q>>3)&7 within each region, applied
// to BOTH the staging source (pre-swizzled global fetch) and the ds_read.
// Pipeline: stage(t+1) -> vmcnt(6|3) -> barrier -> compute(t) -> barrier.
// ---------------------------------------------------------------------------
template <int NTERM, int OMODE, int ROPE>
__global__ __launch_bounds__(512, 1)
void gemm8(const u16* __restrict__ Ah, const u16* __restrict__ Al,
           const u16* __restrict__ Bh, const u16* __restrict__ Bl,
           float* __restrict__ Cf, u16* __restrict__ Ch, u16* __restrict__ Cl,
           const float* __restrict__ cosT, const float* __restrict__ sinT,
           float scale, int M, int N, int K) {
  constexpr int BUF = (NTERM == 3) ? 24576 : 12288;   // u16 per buffer
  constexpr int BHI = (NTERM == 3) ? 16384 : 8192;    // B-hi region base
  __shared__ u16 SM[2 * BUF];
  const int bn = blockIdx.x, bm = blockIdx.y;
  const int t = threadIdx.x;
  const int w = t >> 6, lane = t & 63;
  const int l31 = lane & 31, hi = lane >> 5;
  const int wm = w >> 1, wn = w & 1;

  const size_t arow0 = (size_t)bm * 256, brow0 = (size_t)bn * 128;

  // ---- staging: linear LDS dest, pre-swizzled global source ----
  const int pA0 = 128 * w + lane;          // 16B-chunk index within A region
  const int pA1 = pA0 + 64;
  const int pB0 = 64 * w + lane;
  const int qA0 = pA0 ^ ((pA0 >> 3) & 7);
  const int qA1 = pA1 ^ ((pA1 >> 3) & 7);
  const int qB0 = pB0 ^ ((pB0 >> 3) & 7);
  const size_t gA0 = (arow0 + (qA0 >> 2)) * (size_t)K + (qA0 & 3) * 8;
  const size_t gA1 = (arow0 + (qA1 >> 2)) * (size_t)K + (qA1 & 3) * 8;
  const size_t gB0 = (brow0 + (qB0 >> 2)) * (size_t)K + (qB0 & 3) * 8;

  auto stage = [&](int k0, int bp) {
    u16* P = &SM[bp * BUF];
    gld16(&Ah[gA0 + k0], P + 1024 * w);
    gld16(&Ah[gA1 + k0], P + 1024 * w + 512);
    gld16(&Bh[gB0 + k0], P + BHI + 512 * w);
    if constexpr (NTERM == 3) {
      gld16(&Al[gA0 + k0], P + 8192 + 1024 * w);
      gld16(&Al[gA1 + k0], P + 8192 + 1024 * w + 512);
      gld16(&Bl[gB0 + k0], P + BHI + 4096 + 512 * w);
    }
  };

  // ---- swizzled read offsets (u16 units, within region) ----
  auto aoff = [&](int fm, int ks) {
    int q = ((64 * wm + 32 * fm + l31) << 2) | (2 * ks + hi);
    q ^= (q >> 3) & 7;
    return q * 8;
  };
  auto boff = [&](int fn, int ks) {
    int q = ((32 * wn + 64 * fn + l31) << 2) | (2 * ks + hi);
    q ^= (q >> 3) & 7;
    return q * 8;
  };

  f32x16 acc[2][2];
#pragma unroll
  for (int fm = 0; fm < 2; ++fm)
#pragma unroll
    for (int fn = 0; fn < 2; ++fn)
#pragma unroll
      for (int r = 0; r < 16; ++r) acc[fm][fn][r] = 0.f;

  stage(0, 0);
  const int NK = K >> 5;
  int bp = 0;
  for (int kt = 0; kt < NK; ++kt) {
    if (kt + 1 < NK) {
      stage((kt + 1) * 32, bp ^ 1);
      if constexpr (NTERM == 3)
        asm volatile("s_waitcnt vmcnt(6)" ::: "memory");
      else
        asm volatile("s_waitcnt vmcnt(3)" ::: "memory");
    } else {
      asm volatile("s_waitcnt vmcnt(0)" ::: "memory");
    }
    __builtin_amdgcn_sched_barrier(0);
    __builtin_amdgcn_s_barrier();
    __builtin_amdgcn_sched_barrier(0);

    const u16* P = &SM[bp * BUF];
    __builtin_amdgcn_s_setprio(1);
#pragma unroll
    for (int ks = 0; ks < 2; ++ks) {
      s16x8 a_h[2], a_l[2], b_h[2], b_l[2];
#pragma unroll
      for (int fm = 0; fm < 2; ++fm) {
        a_h[fm] = *(const s16x8*)&P[aoff(fm, ks)];
        if constexpr (NTERM == 3)
          a_l[fm] = *(const s16x8*)&P[8192 + aoff(fm, ks)];
      }
#pragma unroll
      for (int fn = 0; fn < 2; ++fn) {
        b_h[fn] = *(const s16x8*)&P[BHI + boff(fn, ks)];
        if constexpr (NTERM == 3)
          b_l[fn] = *(const s16x8*)&P[BHI + 4096 + boff(fn, ks)];
      }
#pragma unroll
      for (int fm = 0; fm < 2; ++fm)
#pragma unroll
        for (int fn = 0; fn < 2; ++fn) {
          acc[fm][fn] = MFMA32(a_h[fm], b_h[fn], acc[fm][fn]);
          if constexpr (NTERM == 3) {
            acc[fm][fn] = MFMA32(a_h[fm], b_l[fn], acc[fm][fn]);
            acc[fm][fn] = MFMA32(a_l[fm], b_h[fn], acc[fm][fn]);
          }
        }
    }
    __builtin_amdgcn_s_setprio(0);
    __builtin_amdgcn_s_barrier();
    bp ^= 1;
  }

  // ---- epilogue ----
  if constexpr (ROPE) {
    // tile is head-aligned (BN=128 = one head). hd in [0,64) pairs with hd+64.
    const int hd = 32 * wn + l31;
#pragma unroll
    for (int fm = 0; fm < 2; ++fm)
#pragma unroll
      for (int r = 0; r < 16; ++r) {
        const int row = bm * 256 + 64 * wm + 32 * fm + (r & 3) + 8 * (r >> 2) + 4 * hi;
        const int s = row & 2047;
        const float cs = cosT[s * 64 + hd], sn = sinT[s * 64 + hd];
        const float q1 = acc[fm][0][r], q2 = acc[fm][1][r];
        const float o1 = (q1 * cs - q2 * sn) * scale;
        const float o2 = (q2 * cs + q1 * sn) * scale;
        const size_t p1 = (size_t)row * N + bn * 128 + hd;
        const u16 h1 = f2bf(o1);
        Ch[p1] = h1; Cl[p1] = f2bf(o1 - bf2f(h1));
        const u16 h2 = f2bf(o2);
        Ch[p1 + 64] = h2; Cl[p1 + 64] = f2bf(o2 - bf2f(h2));
      }
  } else {
#pragma unroll
    for (int fm = 0; fm < 2; ++fm)
#pragma unroll
      for (int fn = 0; fn < 2; ++fn)
#pragma unroll
        for (int r = 0; r < 16; ++r) {
          const int row = bm * 256 + 64 * wm + 32 * fm + (r & 3) + 8 * (r >> 2) + 4 * hi;
          const int col = bn * 128 + 32 * wn + 64 * fn + l31;
          const float v = acc[fm][fn][r];
          if constexpr (OMODE == 0) {
            Cf[(size_t)row * N + col] = v;
          } else if constexpr (OMODE == 1) {
            const u16 hv = f2bf(v);
            Ch[(size_t)row * N + col] = hv;
            Cl[(size_t)row * N + col] = f2bf(v - bf2f(hv));
          } else {
            Ch[(size_t)row * N + col] = f2bf(v);
          }
        }
  }
}

// ---------------------------------------------------------------------------
// Flash attention, causal, 32x32x16 swapped-operand MFMA, counted-vmcnt
// double-buffered pipeline, QBLK=128, k-split wave pairs.  (unchanged R8)
// ---------------------------------------------------------------------------
__global__ __launch_bounds__(512, 2)
void attn(const u16* __restrict__ Qh, const u16* __restrict__ Ql,
          const u16* __restrict__ Kh, const u16* __restrict__ Kl,
          const u16* __restrict__ Vt, u16* __restrict__ Ctx) {
  __shared__ u16 SMEM[65536];               // 128 KB
  // buf p at u16 p*24576: Kh [0,8192) Kl [8192,16384) V [16384,24576)
  // scratch at u16 49152 (32 KB): m/l exchange, then O exchange, then Os

  const int t = threadIdx.x;
  const int w = t >> 6, lane = t & 63;
  const int l31 = lane & 31, hi = lane >> 5;
  const int swz = (l31 & 7) << 3;
  const int j = w >> 1, kh = w & 1;         // q-slice, k-half

  // ---- XCD remap: 16 blocks of a head on one XCD; unique task pairs ----
  const int bid = (int)blockIdx.x + 8 * (int)blockIdx.y + 128 * (int)blockIdx.z;
  const int xcd = bid & 7, slot = bid >> 3;          // slot 0..31
  const int h = xcd * 2 + (slot >> 4);
  const int rem = slot & 15;
  const int qtA = rem & 7, bA = rem >> 3;            // task A: (bA, qtA)
  // task B: (1-bA, 15-qtA).  Coverage: qt<=7 via A, qt>=8 via B, each once.

  // ---- staging source offsets (u16 units), pre-swizzled ----
  const int offK0 = (8 * w + (lane >> 4)) * 2048 + (((lane & 15) ^ ((lane >> 4) & 7)) * 8);
  const int offK1 = (8 * w + 4 + (lane >> 4)) * 2048 + (((lane & 15) ^ ((4 + (lane >> 4)) & 7)) * 8);
  const int offV0 = (16 * w + (lane >> 3)) * 4096 + (((lane & 7) ^ ((lane >> 3) & 7)) * 8);
  const int offV1 = offV0 + 8 * 4096;

  auto stage = [&](const u16* gK, const u16* gKlo, const u16* gV, int kt, int bp) {
    u16* B = &SMEM[bp * 24576];
    const int ka = kt * 131072;   // kt*64*2048
    const int va = kt * 64;
    gld16(gK + ka + offK0, B + 1024 * w);
    gld16(gK + ka + offK1, B + 1024 * w + 512);
    gld16(gKlo + ka + offK0, B + 8192 + 1024 * w);
    gld16(gKlo + ka + offK1, B + 8192 + 1024 * w + 512);
    gld16(gV + va + offV0, B + 16384 + 1024 * w);
    gld16(gV + va + offV1, B + 16384 + 1024 * w + 512);
  };

  int bufph = 0;
  // prime: task A tile 0
  {
    const u16* gK0 = Kh + ((size_t)(bA * 2048)) * 2048 + h * 128;
    const u16* gL0 = Kl + ((size_t)(bA * 2048)) * 2048 + h * 128;
    const u16* gV0 = Vt + (size_t)(h * 128) * 4096 + bA * 2048;
    stage(gK0, gL0, gV0, 0, 0);
  }

  for (int task = 0; task < 2; ++task) {
    const int qt = task ? 15 - qtA : qtA;
    const int bb = task ? 1 - bA : bA;
    const u16* gK0 = Kh + ((size_t)(bb * 2048)) * 2048 + h * 128;
    const u16* gL0 = Kl + ((size_t)(bb * 2048)) * 2048 + h * 128;
    const u16* gV0 = Vt + (size_t)(h * 128) * 4096 + bb * 2048;
    // next task's pointers (for cross-task prefetch)
    const int nb = 1 - bb;
    const u16* nK0 = Kh + ((size_t)(nb * 2048)) * 2048 + h * 128;
    const u16* nL0 = Kl + ((size_t)(nb * 2048)) * 2048 + h * 128;
    const u16* nV0 = Vt + (size_t)(h * 128) * 4096 + nb * 2048;

    const int q0 = qt * 128 + 32 * j;          // wave's first q row
    const int qg = q0 + l31;                   // this lane's q row
    // ---- Q fragments ----
    s16x8 qfh[8], qfl[8];
    {
      const size_t qbase = ((size_t)(bb * 2048 + qg)) * 2048 + h * 128 + 8 * hi;
#pragma unroll
      for (int s = 0; s < 8; ++s) {
        qfh[s] = *(const s16x8*)&Qh[qbase + 16 * s];
        qfl[s] = *(const s16x8*)&Ql[qbase + 16 * s];
      }
    }

    float m_run = -3.0e38f, l_run = 0.f;
    f32x16 o[4];
#pragma unroll
    for (int d = 0; d < 4; ++d)
#pragma unroll
      for (int r = 0; r < 16; ++r) o[d][r] = 0.f;

    const int nt = 2 * qt + 2;
    for (int kt = 0; kt < nt; ++kt) {
      // ---- issue next stage (stays in flight across barriers) ----
      bool staged = true;
      if (kt + 1 < nt)      stage(gK0, gL0, gV0, kt + 1, bufph ^ 1);
      else if (task == 0)   stage(nK0, nL0, nV0, 0, bufph ^ 1);
      else                  staged = false;
      if (staged) asm volatile("s_waitcnt vmcnt(6)" ::: "memory");
      else        asm volatile("s_waitcnt vmcnt(0)" ::: "memory");
      __builtin_amdgcn_sched_barrier(0);
      __builtin_amdgcn_s_barrier();
      __builtin_amdgcn_sched_barrier(0);

      const int kb0 = kt * 64 + 32 * kh;       // wave's k-half base
      const bool active = (q0 + 31) >= kb0;
      if (active) {
        const u16* Kb = &SMEM[bufph * 24576];
        const u16* Lb = Kb + 8192;
        const u16* Vb = Kb + 16384;
        // ---- S^T (wave's 32k x 32q block), split precision 3-term ----
        f32x16 acc;
#pragma unroll
        for (int r = 0; r < 16; ++r) acc[r] = 0.f;
        __builtin_amdgcn_s_setprio(1);
#pragma unroll
        for (int s = 0; s < 8; ++s) {
          const int col = 16 * s + 8 * hi;
          const s16x8 kha = *(const s16x8*)&Kb[((32 * kh + l31) * 128 + col) ^ swz];
          const s16x8 kla = *(const s16x8*)&Lb[((32 * kh + l31) * 128 + col) ^ swz];
          acc = MFMA32(kha, qfh[s], acc);
          acc = MFMA32(kla, qfh[s], acc);
          acc = MFMA32(kha, qfl[s], acc);
        }
        __builtin_amdgcn_s_setprio(0);

        // ---- causal mask + online softmax (lane-local, wave-private) ----
        const bool partial = (kb0 + 31) > q0;
        float mx = -3.0e38f;
#pragma unroll
        for (int r = 0; r < 16; ++r) {
          const int koff = (r & 3) + 8 * (r >> 2) + 4 * hi;
          float v = acc[r];
          if (partial && (kb0 + koff > qg)) v = -3.0e38f;
          acc[r] = v;
          mx = fmaxf(mx, v);
        }
        mx = fmaxf(mx, __shfl_xor(mx, 32));    // combine hi halves (same q)
        const float mn = fmaxf(m_run, mx);
        const float al = __expf(m_run - mn);
        m_run = mn;
        float rs = 0.f;
#pragma unroll
        for (int r = 0; r < 16; ++r) {
          const float e = __expf(acc[r] - mn);
          acc[r] = e;
          rs += e;
        }
        rs += __shfl_xor(rs, 32);
        l_run = l_run * al + rs;
#pragma unroll
        for (int d = 0; d < 4; ++d)
#pragma unroll
          for (int r = 0; r < 16; ++r) o[d][r] *= al;

        // ---- pack P -> PV B-fragments (cvt_pk + permlane32_swap) ----
        s16x8 pb[2];
#pragma unroll
        for (int tt = 0; tt < 2; ++tt) {
          const int q2A = 2 * tt;
          const float e0 = acc[4 * q2A + 0], e1 = acc[4 * q2A + 1];
          const float e2 = acc[4 * q2A + 2], e3 = acc[4 * q2A + 3];
          const float f0 = acc[4 * q2A + 4], f1 = acc[4 * q2A + 5];
          const float f2 = acc[4 * q2A + 6], f3 = acc[4 * q2A + 7];
          unsigned a0 = cvtpk_bf16(e0, e1);
          unsigned a1 = cvtpk_bf16(e2, e3);
          unsigned b0 = cvtpk_bf16(f0, f1);
          unsigned b1 = cvtpk_bf16(f2, f3);
          asm volatile("v_permlane32_swap_b32 %0, %1" : "+v"(a0), "+v"(b0));
          asm volatile("v_permlane32_swap_b32 %0, %1" : "+v"(a1), "+v"(b1));
          union { unsigned u[4]; s16x8 v; } pk;
          pk.u[0] = a0; pk.u[1] = a1; pk.u[2] = b0; pk.u[3] = b1;
          pb[tt] = pk.v;
        }

        // ---- O^T += V^T[:, wave's k-half] * P ----
        __builtin_amdgcn_s_setprio(1);
#pragma unroll
        for (int d = 0; d < 4; ++d) {
#pragma unroll
          for (int tt = 0; tt < 2; ++tt) {
            const s16x8 va = *(const s16x8*)
                &Vb[((32 * d + l31) * 64 + 16 * (2 * kh + tt) + 8 * hi) ^ swz];
            o[d] = MFMA32(va, pb[tt], o[d]);
          }
        }
        __builtin_amdgcn_s_setprio(0);
      }
      __builtin_amdgcn_s_barrier();
      bufph ^= 1;
    }

    // ======== epilogue: merge k-half wave pairs, normalize, store ========
    float* Sf = (float*)&SMEM[49152];          // 32KB scratch as f32[8192]
    // (1) m/l exchange
    Sf[w * 64 + lane] = m_run;
    Sf[512 + w * 64 + lane] = l_run;
    asm volatile("s_waitcnt lgkmcnt(0)" ::: "memory");
    __builtin_amdgcn_s_barrier();
    const float mOth = Sf[(w ^ 1) * 64 + lane];
    const float lOth = Sf[512 + (w ^ 1) * 64 + lane];
    const float mC = fmaxf(m_run, mOth);
    const float eS = __expf(m_run - mC);
    const float eO = __expf(mOth - mC);
    const float lC = eS * l_run + eO * lOth;
    // scale own partial O (odd waves hand over pre-scaled)
#pragma unroll
    for (int d = 0; d < 4; ++d)
#pragma unroll
      for (int r = 0; r < 16; ++r) o[d][r] *= eS;
    __builtin_amdgcn_s_barrier();              // m/l reads done before reuse
    // (2) O exchange: odd wave -> even wave, 2 rounds of 32KB
#pragma unroll
    for (int round = 0; round < 2; ++round) {
      if ((w >> 2) == round && kh == 1) {
        const int sl = j & 1;
#pragma unroll
        for (int d = 0; d < 4; ++d)
#pragma unroll
          for (int rr = 0; rr < 4; ++rr) {
            float4v c;
            c[0] = o[d][4 * rr + 0]; c[1] = o[d][4 * rr + 1];
            c[2] = o[d][4 * rr + 2]; c[3] = o[d][4 * rr + 3];
            const int cidx = 4 * (d * 4 + rr);
            *(float4v*)&Sf[sl * 4096 + ((lane * 64 + cidx) ^ ((lane & 7) << 2))] = c;
          }
      }
      asm volatile("s_waitcnt lgkmcnt(0)" ::: "memory");
      __builtin_amdgcn_s_barrier();
      if ((w >> 2) == round && kh == 0) {
        const int sl = j & 1;
#pragma unroll
        for (int d = 0; d < 4; ++d)
#pragma unroll
          for (int rr = 0; rr < 4; ++rr) {
            const int cidx = 4 * (d * 4 + rr);
            const float4v c =
                *(const float4v*)&Sf[sl * 4096 + ((lane * 64 + cidx) ^ ((lane & 7) << 2))];
            o[d][4 * rr + 0] += c[0]; o[d][4 * rr + 1] += c[1];
            o[d][4 * rr + 2] += c[2]; o[d][4 * rr + 3] += c[3];
          }
      }
      __builtin_amdgcn_s_barrier();
    }
    // (3) even waves: normalize + transposed bf16 write to Os
    u16* Os = &SMEM[49152];                    // [128][128] u16, swizzled
    if (kh == 0) {
      const float inv_l = 1.0f / lC;
      const int rl = 32 * j + l31;
#pragma unroll
      for (int d = 0; d < 4; ++d)
#pragma unroll
        for (int r = 0; r < 16; r += 2) {
          const int dd = 32 * d + (r & 3) + 8 * (r >> 2) + 4 * hi;
          const unsigned pr = cvtpk_bf16(o[d][r] * inv_l, o[d][r + 1] * inv_l);
          *(unsigned*)&Os[(rl * 128 + dd) ^ ((rl & 7) << 3)] = pr;
        }
    }
    asm volatile("s_waitcnt lgkmcnt(0)" ::: "memory");
    __builtin_amdgcn_s_barrier();
    // (4) coalesced store, all 8 waves
    {
      const int rr = t >> 2, cb = (t & 3) * 32;
      const size_t ob =
          ((size_t)(bb * 2048 + qt * 128 + rr)) * 2048 + h * 128 + cb;
#pragma unroll
      for (int p = 0; p < 4; ++p)
        *(u16x8*)&Ctx[ob + 8 * p] =
            *(const u16x8*)&Os[(rr * 128 + cb + 8 * p) ^ ((rr & 7) << 3)];
    }
    asm volatile("s_waitcnt lgkmcnt(0)" ::: "memory");
    __builtin_amdgcn_s_barrier();
  }
}

// ---------------------------------------------------------------------------
extern "C" void kernel_launch(void* const* d_in, const int* in_sizes, int n_in,
                              void* d_out, int out_size, void* d_ws, size_t ws_size,
                              hipStream_t stream) {
  const float* x  = (const float*)d_in[0];
  const float* Wq = (const float*)d_in[1];
  const float* Wk = (const float*)d_in[2];
  const float* Wv = (const float*)d_in[3];
  const float* Wo = (const float*)d_in[4];
  float* out = (float*)d_out;

  char* ws = (char*)d_ws;
  size_t off = 0;
  auto alloc = [&](size_t bytes) {
    char* p = ws + off;
    off += (bytes + 255) & ~(size_t)255;
    return p;
  };
  const size_t XE = (size_t)4096 * 2048;   // B*S x H elements
  const size_t WE = (size_t)2048 * 2048;

  u16* xh  = (u16*)alloc(XE * 2);
  u16* xl  = (u16*)alloc(XE * 2);
  u16* Wqh = (u16*)alloc(WE * 2);
  u16* Wql = (u16*)alloc(WE * 2);
  u16* Wkh = (u16*)alloc(WE * 2);
  u16* Wkl = (u16*)alloc(WE * 2);
  u16* Wvh = (u16*)alloc(WE * 2);
  u16* Woh = (u16*)alloc(WE * 2);
  u16* Qhb = (u16*)alloc(XE * 2);
  u16* Qlb = (u16*)alloc(XE * 2);
  u16* Khb = (u16*)alloc(XE * 2);
  u16* Klb = (u16*)alloc(XE * 2);
  u16* Vtb = (u16*)alloc(XE * 2);   // V^T: [2048 dims][4096 seq]
  u16* Ctxb = (u16*)alloc(XE * 2);
  float* cosT = (float*)alloc((size_t)2048 * 64 * 4);
  float* sinT = (float*)alloc((size_t)2048 * 64 * 4);
  (void)ws_size;  // requires ~170 MB of workspace
  (void)in_sizes; (void)n_in; (void)out_size;

  // 1) precision split + RoPE tables
  split_bf16<<<8192, 256, 0, stream>>>(x, xh, xl, (int)(XE / 4));
  split_bf16<<<4096, 256, 0, stream>>>(Wq, Wqh, Wql, (int)(WE / 4));
  split_bf16<<<4096, 256, 0, stream>>>(Wk, Wkh, Wkl, (int)(WE / 4));
  split_bf16<<<4096, 256, 0, stream>>>(Wv, Wvh, nullptr, (int)(WE / 4));
  split_bf16<<<4096, 256, 0, stream>>>(Wo, Woh, nullptr, (int)(WE / 4));
  rope_tab<<<512, 256, 0, stream>>>(cosT, sinT);

  // 2) projections: Q,K split-precision with fused RoPE; V^T directly
  gemm8<3, 1, 1><<<dim3(16, 16), 512, 0, stream>>>(
      xh, xl, Wqh, Wql, nullptr, Qhb, Qlb, cosT, sinT,
      11.313708498984760f, 4096, 2048, 2048);
  gemm8<3, 1, 1><<<dim3(16, 16), 512, 0, stream>>>(
      xh, xl, Wkh, Wkl, nullptr, Khb, Klb, cosT, sinT,
      1.0f, 4096, 2048, 2048);
  // V^T = Wv * x^T :  A=Wv (M=2048 dims), B=x (N=4096 seq)
  gemm8<1, 2, 0><<<dim3(32, 8), 512, 0, stream>>>(
      Wvh, nullptr, xh, nullptr, nullptr, Vtb, nullptr, nullptr, nullptr,
      1.0f, 2048, 4096, 2048);

  // 3) causal flash attention (de-duped task map, k-split wave pairs)
  attn<<<dim3(8, 16, 2), 512, 0, stream>>>(Qhb, Qlb, Khb, Klb, Vtb, Ctxb);

  // 4) output projection -> fp32 d_out
  gemm8<1, 0, 0><<<dim3(16, 16), 512, 0, stream>>>(
      Ctxb, nullptr, Woh, nullptr, out, nullptr, nullptr, nullptr, nullptr,
      1.0f, 4096, 2048, 2048);
}

// Round 6
// 547.029 us; speedup vs baseline: 1.2275x; 1.0034x over previous
//
#include <hip/hip_runtime.h>
#include <cmath>

// ============================================================================
// AutoregressiveGroupQuerySelfAttention  (B=2, S=2048, H=2048, nH=16, D=128)
//
// Round 10: gemm8 memory-side fixes (geometry/schedule unchanged):
//  - XCD-locality remap: XCD x owns bn-pair {PER*x..}, bm-major within XCD.
//    B panels (hi+lo, 2MB) stay L2-resident; A panels stream once per XCD.
//    Cuts L2-fill traffic ~786 -> ~290 MB (was 6 TB/s of L3 delivery).
//  - Triple-buffered LDS (144KB for 3-term, 72KB for 1-term), depth-2
//    prefetch: stage(t+2) -> vmcnt(12) steady (6 loads x 2 tiles in flight).
//    1-term GEMMs get launch_bounds(512,4) -> 2 blocks/CU.
//  - attn unchanged (R8 de-duped task map, k-split wave pairs).
// ============================================================================

typedef unsigned short u16;
typedef __attribute__((ext_vector_type(4))) float  f32x4;
typedef __attribute__((ext_vector_type(16))) float f32x16;
typedef __attribute__((ext_vector_type(4))) float  float4v;
typedef __attribute__((ext_vector_type(4))) unsigned short u16x4;
typedef __attribute__((ext_vector_type(8))) unsigned short u16x8;
typedef __attribute__((ext_vector_type(8))) short s16x8;

__device__ __forceinline__ u16 f2bf(float f) {
  unsigned u = __float_as_uint(f);
  u += 0x7FFFu + ((u >> 16) & 1u);            // RNE; inputs are finite
  return (u16)(u >> 16);
}
__device__ __forceinline__ float bf2f(u16 h) {
  return __uint_as_float(((unsigned)h) << 16);
}
__device__ __forceinline__ f32x16 MFMA32(s16x8 a, s16x8 b, f32x16 c) {
  return __builtin_amdgcn_mfma_f32_32x32x16_bf16(a, b, c, 0, 0, 0);
}
__device__ __forceinline__ unsigned cvtpk_bf16(float lo, float hi) {
  unsigned r;
  asm("v_cvt_pk_bf16_f32 %0, %1, %2" : "=v"(r) : "v"(lo), "v"(hi));
  return r;
}
// async global->LDS, 16B per lane; LDS dest = wave-uniform base + lane*16
__device__ __forceinline__ void gld16(const void* g, void* s) {
  __builtin_amdgcn_global_load_lds(
      (const __attribute__((address_space(1))) void*)g,
      (__attribute__((address_space(3))) void*)s, 16, 0, 0);
}

// ---------------------------------------------------------------------------
// fp32 -> bf16 hi (+ optional lo residual).  n4 = element count / 4.
// ---------------------------------------------------------------------------
__global__ void split_bf16(const float* __restrict__ src, u16* __restrict__ hi,
                           u16* __restrict__ lo, int n4) {
  int i = blockIdx.x * 256 + threadIdx.x;
  if (i >= n4) return;
  float4v v = ((const float4v*)src)[i];
  u16x4 hv, lv;
#pragma unroll
  for (int j = 0; j < 4; ++j) {
    float f = v[j];
    u16 h = f2bf(f);
    hv[j] = h;
    lv[j] = f2bf(f - bf2f(h));
  }
  ((u16x4*)hi)[i] = hv;
  if (lo) ((u16x4*)lo)[i] = lv;
}

// ---------------------------------------------------------------------------
// RoPE tables in fp64.
// ---------------------------------------------------------------------------
__global__ void rope_tab(float* __restrict__ cosT, float* __restrict__ sinT) {
  int idx = blockIdx.x * 256 + threadIdx.x;   // 2048*64
  int i = idx & 63, s = idx >> 6;
  double invf = pow(10000.0, -(double)i / 64.0);
  double ang = (double)s * invf;
  cosT[idx] = (float)cos(ang);
  sinT[idx] = (float)sin(ang);
}

// ---------------------------------------------------------------------------
// gemm8:  C(MxN) = A(MxK) * B(NxK)^T, bf16 inputs, fp32 accumulate.
// NTERM==3: split precision (hh+hl+lh).
// OMODE: 0 fp32, 1 bf16 hi/lo, 2 bf16.   ROPE: fuse rotation in epilogue.
// GX: launch grid.x (8*PER); XCD remap: xcd owns bn in [PER*xcd, PER*xcd+PER),
// bm-major within xcd (assumes bid%8 -> XCD round-robin; speed-only).
// 256x128 tile, BK=32, 512 thr = 8 waves (wm=w>>1, wn=w&1), per-wave 64x64.
// Triple-buffered LDS, depth-2 prefetch: stage(t+2) -> vmcnt(12|6) -> barrier
// -> ds_read+MFMA(setprio) -> barrier. vmcnt never drained mid-loop.
// Swizzle: 16B-chunk involution q ^= (q>>3)&7, pre-swizzled global source +
// swizzled ds_read (LDS dest linear).
// ---------------------------------------------------------------------------
template <int NTERM, int OMODE, int ROPE, int GX>
__global__ __launch_bounds__(512, NTERM == 3 ? 1 : 4)
void gemm8(const u16* __restrict__ Ah, const u16* __restrict__ Al,
           const u16* __restrict__ Bh, const u16* __restrict__ Bl,
           float* __restrict__ Cf, u16* __restrict__ Ch, u16* __restrict__ Cl,
           const float* __restrict__ cosT, const float* __restrict__ sinT,
           float scale, int M, int N, int K) {
  constexpr int BUF = (NTERM == 3) ? 24576 : 12288;   // u16 per buffer
  constexpr int BHI = (NTERM == 3) ? 16384 : 8192;    // B-hi region base
  constexpr int PER = GX / 8;                          // bn per XCD
  constexpr int PSH = (PER == 2) ? 1 : 2;
  static_assert(PER == 2 || PER == 4, "grid.x must be 16 or 32");
  __shared__ u16 SM[3 * BUF];
  const int t = threadIdx.x;
  const int w = t >> 6, lane = t & 63;
  const int l31 = lane & 31, hi = lane >> 5;
  const int wm = w >> 1, wn = w & 1;

  // ---- XCD-locality remap ----
  const int bid = (int)blockIdx.x + GX * (int)blockIdx.y;
  const int xcd = bid & 7, slot = bid >> 3;
  const int bn = PER * xcd + (slot & (PER - 1));
  const int bm = slot >> PSH;

  const size_t arow0 = (size_t)bm * 256, brow0 = (size_t)bn * 128;

  // ---- staging: linear LDS dest, pre-swizzled global source ----
  const int pA0 = 128 * w + lane;          // 16B-chunk index within A region
  const int pA1 = pA0 + 64;
  const int pB0 = 64 * w + lane;
  const int qA0 = pA0 ^ ((pA0 >> 3) & 7);
  const int qA1 = pA1 ^ ((pA1 >> 3) & 7);
  const int qB0 = pB0 ^ ((pB0 >> 3) & 7);
  const size_t gA0 = (arow0 + (qA0 >> 2)) * (size_t)K + (qA0 & 3) * 8;
  const size_t gA1 = (arow0 + (qA1 >> 2)) * (size_t)K + (qA1 & 3) * 8;
  const size_t gB0 = (brow0 + (qB0 >> 2)) * (size_t)K + (qB0 & 3) * 8;

  auto stage = [&](int k0, int bp) {
    u16* P = &SM[bp * BUF];
    gld16(&Ah[gA0 + k0], P + 1024 * w);
    gld16(&Ah[gA1 + k0], P + 1024 * w + 512);
    gld16(&Bh[gB0 + k0], P + BHI + 512 * w);
    if constexpr (NTERM == 3) {
      gld16(&Al[gA0 + k0], P + 8192 + 1024 * w);
      gld16(&Al[gA1 + k0], P + 8192 + 1024 * w + 512);
      gld16(&Bl[gB0 + k0], P + BHI + 4096 + 512 * w);
    }
  };

  // ---- swizzled read offsets (u16 units, within region) ----
  auto aoff = [&](int fm, int ks) {
    int q = ((64 * wm + 32 * fm + l31) << 2) | (2 * ks + hi);
    q ^= (q >> 3) & 7;
    return q * 8;
  };
  auto boff = [&](int fn, int ks) {
    int q = ((32 * wn + 64 * fn + l31) << 2) | (2 * ks + hi);
    q ^= (q >> 3) & 7;
    return q * 8;
  };

  f32x16 acc[2][2];
#pragma unroll
  for (int fm = 0; fm < 2; ++fm)
#pragma unroll
    for (int fn = 0; fn < 2; ++fn)
#pragma unroll
      for (int r = 0; r < 16; ++r) acc[fm][fn][r] = 0.f;

  const int NK = K >> 5;
  stage(0, 0);
  if (NK > 1) stage(32, 1);
  int cur = 0, nxt = 1, fut = 2;
  for (int kt = 0; kt < NK; ++kt) {
    if (kt + 2 < NK) {
      stage((kt + 2) * 32, fut);
      if constexpr (NTERM == 3)
        asm volatile("s_waitcnt vmcnt(12)" ::: "memory");
      else
        asm volatile("s_waitcnt vmcnt(6)" ::: "memory");
    } else if (kt + 1 < NK) {
      if constexpr (NTERM == 3)
        asm volatile("s_waitcnt vmcnt(6)" ::: "memory");
      else
        asm volatile("s_waitcnt vmcnt(3)" ::: "memory");
    } else {
      asm volatile("s_waitcnt vmcnt(0)" ::: "memory");
    }
    __builtin_amdgcn_sched_barrier(0);
    __builtin_amdgcn_s_barrier();
    __builtin_amdgcn_sched_barrier(0);

    const u16* P = &SM[cur * BUF];
    __builtin_amdgcn_s_setprio(1);
#pragma unroll
    for (int ks = 0; ks < 2; ++ks) {
      s16x8 a_h[2], a_l[2], b_h[2], b_l[2];
#pragma unroll
      for (int fm = 0; fm < 2; ++fm) {
        a_h[fm] = *(const s16x8*)&P[aoff(fm, ks)];
        if constexpr (NTERM == 3)
          a_l[fm] = *(const s16x8*)&P[8192 + aoff(fm, ks)];
      }
#pragma unroll
      for (int fn = 0; fn < 2; ++fn) {
        b_h[fn] = *(const s16x8*)&P[BHI + boff(fn, ks)];
        if constexpr (NTERM == 3)
          b_l[fn] = *(const s16x8*)&P[BHI + 4096 + boff(fn, ks)];
      }
#pragma unroll
      for (int fm = 0; fm < 2; ++fm)
#pragma unroll
        for (int fn = 0; fn < 2; ++fn) {
          acc[fm][fn] = MFMA32(a_h[fm], b_h[fn], acc[fm][fn]);
          if constexpr (NTERM == 3) {
            acc[fm][fn] = MFMA32(a_h[fm], b_l[fn], acc[fm][fn]);
            acc[fm][fn] = MFMA32(a_l[fm], b_h[fn], acc[fm][fn]);
          }
        }
    }
    __builtin_amdgcn_s_setprio(0);
    __builtin_amdgcn_s_barrier();
    const int tmp = cur; cur = nxt; nxt = fut; fut = tmp;
  }

  // ---- epilogue ----
  if constexpr (ROPE) {
    // tile is head-aligned (BN=128 = one head). hd in [0,64) pairs with hd+64.
    const int hd = 32 * wn + l31;
#pragma unroll
    for (int fm = 0; fm < 2; ++fm)
#pragma unroll
      for (int r = 0; r < 16; ++r) {
        const int row = bm * 256 + 64 * wm + 32 * fm + (r & 3) + 8 * (r >> 2) + 4 * hi;
        const int s = row & 2047;
        const float cs = cosT[s * 64 + hd], sn = sinT[s * 64 + hd];
        const float q1 = acc[fm][0][r], q2 = acc[fm][1][r];
        const float o1 = (q1 * cs - q2 * sn) * scale;
        const float o2 = (q2 * cs + q1 * sn) * scale;
        const size_t p1 = (size_t)row * N + bn * 128 + hd;
        const u16 h1 = f2bf(o1);
        Ch[p1] = h1; Cl[p1] = f2bf(o1 - bf2f(h1));
        const u16 h2 = f2bf(o2);
        Ch[p1 + 64] = h2; Cl[p1 + 64] = f2bf(o2 - bf2f(h2));
      }
  } else {
#pragma unroll
    for (int fm = 0; fm < 2; ++fm)
#pragma unroll
      for (int fn = 0; fn < 2; ++fn)
#pragma unroll
        for (int r = 0; r < 16; ++r) {
          const int row = bm * 256 + 64 * wm + 32 * fm + (r & 3) + 8 * (r >> 2) + 4 * hi;
          const int col = bn * 128 + 32 * wn + 64 * fn + l31;
          const float v = acc[fm][fn][r];
          if constexpr (OMODE == 0) {
            Cf[(size_t)row * N + col] = v;
          } else if constexpr (OMODE == 1) {
            const u16 hv = f2bf(v);
            Ch[(size_t)row * N + col] = hv;
            Cl[(size_t)row * N + col] = f2bf(v - bf2f(hv));
          } else {
            Ch[(size_t)row * N + col] = f2bf(v);
          }
        }
  }
}

// ---------------------------------------------------------------------------
// Flash attention, causal, 32x32x16 swapped-operand MFMA, counted-vmcnt
// double-buffered pipeline, QBLK=128, k-split wave pairs.  (unchanged R8)
// ---------------------------------------------------------------------------
__global__ __launch_bounds__(512, 2)
void attn(const u16* __restrict__ Qh, const u16* __restrict__ Ql,
          const u16* __restrict__ Kh, const u16* __restrict__ Kl,
          const u16* __restrict__ Vt, u16* __restrict__ Ctx) {
  __shared__ u16 SMEM[65536];               // 128 KB
  // buf p at u16 p*24576: Kh [0,8192) Kl [8192,16384) V [16384,24576)
  // scratch at u16 49152 (32 KB): m/l exchange, then O exchange, then Os

  const int t = threadIdx.x;
  const int w = t >> 6, lane = t & 63;
  const int l31 = lane & 31, hi = lane >> 5;
  const int swz = (l31 & 7) << 3;
  const int j = w >> 1, kh = w & 1;         // q-slice, k-half

  // ---- XCD remap: 16 blocks of a head on one XCD; unique task pairs ----
  const int bid = (int)blockIdx.x + 8 * (int)blockIdx.y + 128 * (int)blockIdx.z;
  const int xcd = bid & 7, slot = bid >> 3;          // slot 0..31
  const int h = xcd * 2 + (slot >> 4);
  const int rem = slot & 15;
  const int qtA = rem & 7, bA = rem >> 3;            // task A: (bA, qtA)
  // task B: (1-bA, 15-qtA).  Coverage: qt<=7 via A, qt>=8 via B, each once.

  // ---- staging source offsets (u16 units), pre-swizzled ----
  const int offK0 = (8 * w + (lane >> 4)) * 2048 + (((lane & 15) ^ ((lane >> 4) & 7)) * 8);
  const int offK1 = (8 * w + 4 + (lane >> 4)) * 2048 + (((lane & 15) ^ ((4 + (lane >> 4)) & 7)) * 8);
  const int offV0 = (16 * w + (lane >> 3)) * 4096 + (((lane & 7) ^ ((lane >> 3) & 7)) * 8);
  const int offV1 = offV0 + 8 * 4096;

  auto stage = [&](const u16* gK, const u16* gKlo, const u16* gV, int kt, int bp) {
    u16* B = &SMEM[bp * 24576];
    const int ka = kt * 131072;   // kt*64*2048
    const int va = kt * 64;
    gld16(gK + ka + offK0, B + 1024 * w);
    gld16(gK + ka + offK1, B + 1024 * w + 512);
    gld16(gKlo + ka + offK0, B + 8192 + 1024 * w);
    gld16(gKlo + ka + offK1, B + 8192 + 1024 * w + 512);
    gld16(gV + va + offV0, B + 16384 + 1024 * w);
    gld16(gV + va + offV1, B + 16384 + 1024 * w + 512);
  };

  int bufph = 0;
  // prime: task A tile 0
  {
    const u16* gK0 = Kh + ((size_t)(bA * 2048)) * 2048 + h * 128;
    const u16* gL0 = Kl + ((size_t)(bA * 2048)) * 2048 + h * 128;
    const u16* gV0 = Vt + (size_t)(h * 128) * 4096 + bA * 2048;
    stage(gK0, gL0, gV0, 0, 0);
  }

  for (int task = 0; task < 2; ++task) {
    const int qt = task ? 15 - qtA : qtA;
    const int bb = task ? 1 - bA : bA;
    const u16* gK0 = Kh + ((size_t)(bb * 2048)) * 2048 + h * 128;
    const u16* gL0 = Kl + ((size_t)(bb * 2048)) * 2048 + h * 128;
    const u16* gV0 = Vt + (size_t)(h * 128) * 4096 + bb * 2048;
    // next task's pointers (for cross-task prefetch)
    const int nb = 1 - bb;
    const u16* nK0 = Kh + ((size_t)(nb * 2048)) * 2048 + h * 128;
    const u16* nL0 = Kl + ((size_t)(nb * 2048)) * 2048 + h * 128;
    const u16* nV0 = Vt + (size_t)(h * 128) * 4096 + nb * 2048;

    const int q0 = qt * 128 + 32 * j;          // wave's first q row
    const int qg = q0 + l31;                   // this lane's q row
    // ---- Q fragments ----
    s16x8 qfh[8], qfl[8];
    {
      const size_t qbase = ((size_t)(bb * 2048 + qg)) * 2048 + h * 128 + 8 * hi;
#pragma unroll
      for (int s = 0; s < 8; ++s) {
        qfh[s] = *(const s16x8*)&Qh[qbase + 16 * s];
        qfl[s] = *(const s16x8*)&Ql[qbase + 16 * s];
      }
    }

    float m_run = -3.0e38f, l_run = 0.f;
    f32x16 o[4];
#pragma unroll
    for (int d = 0; d < 4; ++d)
#pragma unroll
      for (int r = 0; r < 16; ++r) o[d][r] = 0.f;

    const int nt = 2 * qt + 2;
    for (int kt = 0; kt < nt; ++kt) {
      // ---- issue next stage (stays in flight across barriers) ----
      bool staged = true;
      if (kt + 1 < nt)      stage(gK0, gL0, gV0, kt + 1, bufph ^ 1);
      else if (task == 0)   stage(nK0, nL0, nV0, 0, bufph ^ 1);
      else                  staged = false;
      if (staged) asm volatile("s_waitcnt vmcnt(6)" ::: "memory");
      else        asm volatile("s_waitcnt vmcnt(0)" ::: "memory");
      __builtin_amdgcn_sched_barrier(0);
      __builtin_amdgcn_s_barrier();
      __builtin_amdgcn_sched_barrier(0);

      const int kb0 = kt * 64 + 32 * kh;       // wave's k-half base
      const bool active = (q0 + 31) >= kb0;
      if (active) {
        const u16* Kb = &SMEM[bufph * 24576];
        const u16* Lb = Kb + 8192;
        const u16* Vb = Kb + 16384;
        // ---- S^T (wave's 32k x 32q block), split precision 3-term ----
        f32x16 acc;
#pragma unroll
        for (int r = 0; r < 16; ++r) acc[r] = 0.f;
        __builtin_amdgcn_s_setprio(1);
#pragma unroll
        for (int s = 0; s < 8; ++s) {
          const int col = 16 * s + 8 * hi;
          const s16x8 kha = *(const s16x8*)&Kb[((32 * kh + l31) * 128 + col) ^ swz];
          const s16x8 kla = *(const s16x8*)&Lb[((32 * kh + l31) * 128 + col) ^ swz];
          acc = MFMA32(kha, qfh[s], acc);
          acc = MFMA32(kla, qfh[s], acc);
          acc = MFMA32(kha, qfl[s], acc);
        }
        __builtin_amdgcn_s_setprio(0);

        // ---- causal mask + online softmax (lane-local, wave-private) ----
        const bool partial = (kb0 + 31) > q0;
        float mx = -3.0e38f;
#pragma unroll
        for (int r = 0; r < 16; ++r) {
          const int koff = (r & 3) + 8 * (r >> 2) + 4 * hi;
          float v = acc[r];
          if (partial && (kb0 + koff > qg)) v = -3.0e38f;
          acc[r] = v;
          mx = fmaxf(mx, v);
        }
        mx = fmaxf(mx, __shfl_xor(mx, 32));    // combine hi halves (same q)
        const float mn = fmaxf(m_run, mx);
        const float al = __expf(m_run - mn);
        m_run = mn;
        float rs = 0.f;
#pragma unroll
        for (int r = 0; r < 16; ++r) {
          const float e = __expf(acc[r] - mn);
          acc[r] = e;
          rs += e;
        }
        rs += __shfl_xor(rs, 32);
        l_run = l_run * al + rs;
#pragma unroll
        for (int d = 0; d < 4; ++d)
#pragma unroll
          for (int r = 0; r < 16; ++r) o[d][r] *= al;

        // ---- pack P -> PV B-fragments (cvt_pk + permlane32_swap) ----
        s16x8 pb[2];
#pragma unroll
        for (int tt = 0; tt < 2; ++tt) {
          const int q2A = 2 * tt;
          const float e0 = acc[4 * q2A + 0], e1 = acc[4 * q2A + 1];
          const float e2 = acc[4 * q2A + 2], e3 = acc[4 * q2A + 3];
          const float f0 = acc[4 * q2A + 4], f1 = acc[4 * q2A + 5];
          const float f2 = acc[4 * q2A + 6], f3 = acc[4 * q2A + 7];
          unsigned a0 = cvtpk_bf16(e0, e1);
          unsigned a1 = cvtpk_bf16(e2, e3);
          unsigned b0 = cvtpk_bf16(f0, f1);
          unsigned b1 = cvtpk_bf16(f2, f3);
          asm volatile("v_permlane32_swap_b32 %0, %1" : "+v"(a0), "+v"(b0));
          asm volatile("v_permlane32_swap_b32 %0, %1" : "+v"(a1), "+v"(b1));
          union { unsigned u[4]; s16x8 v; } pk;
          pk.u[0] = a0; pk.u[1] = a1; pk.u[2] = b0; pk.u[3] = b1;
          pb[tt] = pk.v;
        }

        // ---- O^T += V^T[:, wave's k-half] * P ----
        __builtin_amdgcn_s_setprio(1);
#pragma unroll
        for (int d = 0; d < 4; ++d) {
#pragma unroll
          for (int tt = 0; tt < 2; ++tt) {
            const s16x8 va = *(const s16x8*)
                &Vb[((32 * d + l31) * 64 + 16 * (2 * kh + tt) + 8 * hi) ^ swz];
            o[d] = MFMA32(va, pb[tt], o[d]);
          }
        }
        __builtin_amdgcn_s_setprio(0);
      }
      __builtin_amdgcn_s_barrier();
      bufph ^= 1;
    }

    // ======== epilogue: merge k-half wave pairs, normalize, store ========
    float* Sf = (float*)&SMEM[49152];          // 32KB scratch as f32[8192]
    // (1) m/l exchange
    Sf[w * 64 + lane] = m_run;
    Sf[512 + w * 64 + lane] = l_run;
    asm volatile("s_waitcnt lgkmcnt(0)" ::: "memory");
    __builtin_amdgcn_s_barrier();
    const float mOth = Sf[(w ^ 1) * 64 + lane];
    const float lOth = Sf[512 + (w ^ 1) * 64 + lane];
    const float mC = fmaxf(m_run, mOth);
    const float eS = __expf(m_run - mC);
    const float eO = __expf(mOth - mC);
    const float lC = eS * l_run + eO * lOth;
    // scale own partial O (odd waves hand over pre-scaled)
#pragma unroll
    for (int d = 0; d < 4; ++d)
#pragma unroll
      for (int r = 0; r < 16; ++r) o[d][r] *= eS;
    __builtin_amdgcn_s_barrier();              // m/l reads done before reuse
    // (2) O exchange: odd wave -> even wave, 2 rounds of 32KB
#pragma unroll
    for (int round = 0; round < 2; ++round) {
      if ((w >> 2) == round && kh == 1) {
        const int sl = j & 1;
#pragma unroll
        for (int d = 0; d < 4; ++d)
#pragma unroll
          for (int rr = 0; rr < 4; ++rr) {
            float4v c;
            c[0] = o[d][4 * rr + 0]; c[1] = o[d][4 * rr + 1];
            c[2] = o[d][4 * rr + 2]; c[3] = o[d][4 * rr + 3];
            const int cidx = 4 * (d * 4 + rr);
            *(float4v*)&Sf[sl * 4096 + ((lane * 64 + cidx) ^ ((lane & 7) << 2))] = c;
          }
      }
      asm volatile("s_waitcnt lgkmcnt(0)" ::: "memory");
      __builtin_amdgcn_s_barrier();
      if ((w >> 2) == round && kh == 0) {
        const int sl = j & 1;
#pragma unroll
        for (int d = 0; d < 4; ++d)
#pragma unroll
          for (int rr = 0; rr < 4; ++rr) {
            const int cidx = 4 * (d * 4 + rr);
            const float4v c =
                *(const float4v*)&Sf[sl * 4096 + ((lane * 64 + cidx) ^ ((lane & 7) << 2))];
            o[d][4 * rr + 0] += c[0]; o[d][4 * rr + 1] += c[1];
            o[d][4 * rr + 2] += c[2]; o[d][4 * rr + 3] += c[3];
          }
      }
      __builtin_amdgcn_s_barrier();
    }
    // (3) even waves: normalize + transposed bf16 write to Os
    u16* Os = &SMEM[49152];                    // [128][128] u16, swizzled
    if (kh == 0) {
      const float inv_l = 1.0f / lC;
      const int rl = 32 * j + l31;
#pragma unroll
      for (int d = 0; d < 4; ++d)
#pragma unroll
        for (int r = 0; r < 16; r += 2) {
          const int dd = 32 * d + (r & 3) + 8 * (r >> 2) + 4 * hi;
          const unsigned pr = cvtpk_bf16(o[d][r] * inv_l, o[d][r + 1] * inv_l);
          *(unsigned*)&Os[(rl * 128 + dd) ^ ((rl & 7) << 3)] = pr;
        }
    }
    asm volatile("s_waitcnt lgkmcnt(0)" ::: "memory");
    __builtin_amdgcn_s_barrier();
    // (4) coalesced store, all 8 waves
    {
      const int rr = t >> 2, cb = (t & 3) * 32;
      const size_t ob =
          ((size_t)(bb * 2048 + qt * 128 + rr)) * 2048 + h * 128 + cb;
#pragma unroll
      for (int p = 0; p < 4; ++p)
        *(u16x8*)&Ctx[ob + 8 * p] =
            *(const u16x8*)&Os[(rr * 128 + cb + 8 * p) ^ ((rr & 7) << 3)];
    }
    asm volatile("s_waitcnt lgkmcnt(0)" ::: "memory");
    __builtin_amdgcn_s_barrier();
  }
}

// ---------------------------------------------------------------------------
extern "C" void kernel_launch(void* const* d_in, const int* in_sizes, int n_in,
                              void* d_out, int out_size, void* d_ws, size_t ws_size,
                              hipStream_t stream) {
  const float* x  = (const float*)d_in[0];
  const float* Wq = (const float*)d_in[1];
  const float* Wk = (const float*)d_in[2];
  const float* Wv = (const float*)d_in[3];
  const float* Wo = (const float*)d_in[4];
  float* out = (float*)d_out;

  char* ws = (char*)d_ws;
  size_t off = 0;
  auto alloc = [&](size_t bytes) {
    char* p = ws + off;
    off += (bytes + 255) & ~(size_t)255;
    return p;
  };
  const size_t XE = (size_t)4096 * 2048;   // B*S x H elements
  const size_t WE = (size_t)2048 * 2048;

  u16* xh  = (u16*)alloc(XE * 2);
  u16* xl  = (u16*)alloc(XE * 2);
  u16* Wqh = (u16*)alloc(WE * 2);
  u16* Wql = (u16*)alloc(WE * 2);
  u16* Wkh = (u16*)alloc(WE * 2);
  u16* Wkl = (u16*)alloc(WE * 2);
  u16* Wvh = (u16*)alloc(WE * 2);
  u16* Woh = (u16*)alloc(WE * 2);
  u16* Qhb = (u16*)alloc(XE * 2);
  u16* Qlb = (u16*)alloc(XE * 2);
  u16* Khb = (u16*)alloc(XE * 2);
  u16* Klb = (u16*)alloc(XE * 2);
  u16* Vtb = (u16*)alloc(XE * 2);   // V^T: [2048 dims][4096 seq]
  u16* Ctxb = (u16*)alloc(XE * 2);
  float* cosT = (float*)alloc((size_t)2048 * 64 * 4);
  float* sinT = (float*)alloc((size_t)2048 * 64 * 4);
  (void)ws_size;  // requires ~170 MB of workspace
  (void)in_sizes; (void)n_in; (void)out_size;

  // 1) precision split + RoPE tables
  split_bf16<<<8192, 256, 0, stream>>>(x, xh, xl, (int)(XE / 4));
  split_bf16<<<4096, 256, 0, stream>>>(Wq, Wqh, Wql, (int)(WE / 4));
  split_bf16<<<4096, 256, 0, stream>>>(Wk, Wkh, Wkl, (int)(WE / 4));
  split_bf16<<<4096, 256, 0, stream>>>(Wv, Wvh, nullptr, (int)(WE / 4));
  split_bf16<<<4096, 256, 0, stream>>>(Wo, Woh, nullptr, (int)(WE / 4));
  rope_tab<<<512, 256, 0, stream>>>(cosT, sinT);

  // 2) projections: Q,K split-precision with fused RoPE; V^T directly
  gemm8<3, 1, 1, 16><<<dim3(16, 16), 512, 0, stream>>>(
      xh, xl, Wqh, Wql, nullptr, Qhb, Qlb, cosT, sinT,
      11.313708498984760f, 4096, 2048, 2048);
  gemm8<3, 1, 1, 16><<<dim3(16, 16), 512, 0, stream>>>(
      xh, xl, Wkh, Wkl, nullptr, Khb, Klb, cosT, sinT,
      1.0f, 4096, 2048, 2048);
  // V^T = Wv * x^T :  A=Wv (M=2048 dims), B=x (N=4096 seq)
  gemm8<1, 2, 0, 32><<<dim3(32, 8), 512, 0, stream>>>(
      Wvh, nullptr, xh, nullptr, nullptr, Vtb, nullptr, nullptr, nullptr,
      1.0f, 2048, 4096, 2048);

  // 3) causal flash attention (de-duped task map, k-split wave pairs)
  attn<<<dim3(8, 16, 2), 512, 0, stream>>>(Qhb, Qlb, Khb, Klb, Vtb, Ctxb);

  // 4) output projection -> fp32 d_out
  gemm8<1, 0, 0, 16><<<dim3(16, 16), 512, 0, stream>>>(
      Ctxb, nullptr, Woh, nullptr, out, nullptr, nullptr, nullptr, nullptr,
      1.0f, 4096, 2048, 2048);
}

// Round 7
// 516.658 us; speedup vs baseline: 1.2996x; 1.0588x over previous
//
#include <hip/hip_runtime.h>
#include <cmath>

// ============================================================================
// AutoregressiveGroupQuerySelfAttention  (B=2, S=2048, H=2048, nH=16, D=128)
//
// Round 11: fuse the Q and K projection GEMMs (they share the A operand x).
//  - gemm_qk: 256x128 tile, BK=32, 8 waves, A (hi+lo) staged ONCE per step,
//    B panels for Wq AND Wk staged alongside (64KB/step vs 96KB for the
//    pair) -> -33% staging traffic, -37% ds_reads, shared RoPE tables in
//    the epilogue, 2x MFMA per compute phase (better latency hiding).
//  - Double-buffered 128KB LDS, counted vmcnt(8), XCD-locality remap,
//    sub-phase order {read A, read Bq, q-MFMAs, read Bk, k-MFMAs} to halve
//    live B registers. launch_bounds(512,2) -> 256 VGPR cap.
//  - gemm8 (1-term, V^T + Wo) and attn unchanged from R10.
// ============================================================================

typedef unsigned short u16;
typedef __attribute__((ext_vector_type(4))) float  f32x4;
typedef __attribute__((ext_vector_type(16))) float f32x16;
typedef __attribute__((ext_vector_type(4))) float  float4v;
typedef __attribute__((ext_vector_type(4))) unsigned short u16x4;
typedef __attribute__((ext_vector_type(8))) unsigned short u16x8;
typedef __attribute__((ext_vector_type(8))) short s16x8;

__device__ __forceinline__ u16 f2bf(float f) {
  unsigned u = __float_as_uint(f);
  u += 0x7FFFu + ((u >> 16) & 1u);            // RNE; inputs are finite
  return (u16)(u >> 16);
}
__device__ __forceinline__ float bf2f(u16 h) {
  return __uint_as_float(((unsigned)h) << 16);
}
__device__ __forceinline__ f32x16 MFMA32(s16x8 a, s16x8 b, f32x16 c) {
  return __builtin_amdgcn_mfma_f32_32x32x16_bf16(a, b, c, 0, 0, 0);
}
__device__ __forceinline__ unsigned cvtpk_bf16(float lo, float hi) {
  unsigned r;
  asm("v_cvt_pk_bf16_f32 %0, %1, %2" : "=v"(r) : "v"(lo), "v"(hi));
  return r;
}
// async global->LDS, 16B per lane; LDS dest = wave-uniform base + lane*16
__device__ __forceinline__ void gld16(const void* g, void* s) {
  __builtin_amdgcn_global_load_lds(
      (const __attribute__((address_space(1))) void*)g,
      (__attribute__((address_space(3))) void*)s, 16, 0, 0);
}

// ---------------------------------------------------------------------------
// fp32 -> bf16 hi (+ optional lo residual).  n4 = element count / 4.
// ---------------------------------------------------------------------------
__global__ void split_bf16(const float* __restrict__ src, u16* __restrict__ hi,
                           u16* __restrict__ lo, int n4) {
  int i = blockIdx.x * 256 + threadIdx.x;
  if (i >= n4) return;
  float4v v = ((const float4v*)src)[i];
  u16x4 hv, lv;
#pragma unroll
  for (int j = 0; j < 4; ++j) {
    float f = v[j];
    u16 h = f2bf(f);
    hv[j] = h;
    lv[j] = f2bf(f - bf2f(h));
  }
  ((u16x4*)hi)[i] = hv;
  if (lo) ((u16x4*)lo)[i] = lv;
}

// ---------------------------------------------------------------------------
// RoPE tables in fp64.
// ---------------------------------------------------------------------------
__global__ void rope_tab(float* __restrict__ cosT, float* __restrict__ sinT) {
  int idx = blockIdx.x * 256 + threadIdx.x;   // 2048*64
  int i = idx & 63, s = idx >> 6;
  double invf = pow(10000.0, -(double)i / 64.0);
  double ang = (double)s * invf;
  cosT[idx] = (float)cos(ang);
  sinT[idx] = (float)sin(ang);
}

// ---------------------------------------------------------------------------
// gemm_qk: fused Q/K projection.  Q = x Wq^T (RoPE, *qscale), K = x Wk^T
// (RoPE). Split-precision 3-term on both. 256x128 tile, BK=32, 512 thr =
// 8 waves (wm=w>>1, wn=w&1), per-wave 64x64 per output.
// LDS buffer (u16): A_hi[0,8192) A_lo[8192,16384) Bq_hi[16384,20480)
// Bq_lo[20480,24576) Bk_hi[24576,28672) Bk_lo[28672,32768). 2 bufs = 128KB.
// Counted vmcnt(8) double-buffer; 16B-chunk involution swizzle (pre-swizzled
// global source + swizzled ds_read, LDS dest linear). XCD remap (grid 16x16).
// ---------------------------------------------------------------------------
__global__ __launch_bounds__(512, 2)
void gemm_qk(const u16* __restrict__ xh, const u16* __restrict__ xl,
             const u16* __restrict__ Wqh, const u16* __restrict__ Wql,
             const u16* __restrict__ Wkh, const u16* __restrict__ Wkl,
             u16* __restrict__ Qh, u16* __restrict__ Ql,
             u16* __restrict__ Kh, u16* __restrict__ Kl,
             const float* __restrict__ cosT, const float* __restrict__ sinT,
             float qscale, int M, int N, int K) {
  __shared__ u16 SM[2 * 32768];                 // 128 KB
  const int t = threadIdx.x;
  const int w = t >> 6, lane = t & 63;
  const int l31 = lane & 31, hi = lane >> 5;
  const int wm = w >> 1, wn = w & 1;

  // ---- XCD-locality remap (grid.x = 16 -> 2 bn per XCD) ----
  const int bid = (int)blockIdx.x + 16 * (int)blockIdx.y;
  const int xcd = bid & 7, slot = bid >> 3;
  const int bn = 2 * xcd + (slot & 1);
  const int bm = slot >> 1;

  const size_t arow0 = (size_t)bm * 256, brow0 = (size_t)bn * 128;

  // ---- staging: linear LDS dest, pre-swizzled global source ----
  const int pA0 = 128 * w + lane;          // 16B-chunk index within A region
  const int pA1 = pA0 + 64;
  const int pB0 = 64 * w + lane;
  const int qA0 = pA0 ^ ((pA0 >> 3) & 7);
  const int qA1 = pA1 ^ ((pA1 >> 3) & 7);
  const int qB0 = pB0 ^ ((pB0 >> 3) & 7);
  const size_t gA0 = (arow0 + (qA0 >> 2)) * (size_t)K + (qA0 & 3) * 8;
  const size_t gA1 = (arow0 + (qA1 >> 2)) * (size_t)K + (qA1 & 3) * 8;
  const size_t gB0 = (brow0 + (qB0 >> 2)) * (size_t)K + (qB0 & 3) * 8;

  auto stage = [&](int k0, int bp) {
    u16* P = &SM[bp * 32768];
    gld16(&xh[gA0 + k0], P + 1024 * w);
    gld16(&xh[gA1 + k0], P + 1024 * w + 512);
    gld16(&xl[gA0 + k0], P + 8192 + 1024 * w);
    gld16(&xl[gA1 + k0], P + 8192 + 1024 * w + 512);
    gld16(&Wqh[gB0 + k0], P + 16384 + 512 * w);
    gld16(&Wql[gB0 + k0], P + 20480 + 512 * w);
    gld16(&Wkh[gB0 + k0], P + 24576 + 512 * w);
    gld16(&Wkl[gB0 + k0], P + 28672 + 512 * w);
  };

  // ---- swizzled read offsets (u16 units, within region) ----
  auto aoff = [&](int fm, int ks) {
    int q = ((64 * wm + 32 * fm + l31) << 2) | (2 * ks + hi);
    q ^= (q >> 3) & 7;
    return q * 8;
  };
  auto boff = [&](int fn, int ks) {
    int q = ((32 * wn + 64 * fn + l31) << 2) | (2 * ks + hi);
    q ^= (q >> 3) & 7;
    return q * 8;
  };

  f32x16 accq[2][2], acck[2][2];
#pragma unroll
  for (int fm = 0; fm < 2; ++fm)
#pragma unroll
    for (int fn = 0; fn < 2; ++fn)
#pragma unroll
      for (int r = 0; r < 16; ++r) { accq[fm][fn][r] = 0.f; acck[fm][fn][r] = 0.f; }

  const int NK = K >> 5;
  stage(0, 0);
  int bp = 0;
  for (int kt = 0; kt < NK; ++kt) {
    if (kt + 1 < NK) {
      stage((kt + 1) * 32, bp ^ 1);
      asm volatile("s_waitcnt vmcnt(8)" ::: "memory");
    } else {
      asm volatile("s_waitcnt vmcnt(0)" ::: "memory");
    }
    __builtin_amdgcn_sched_barrier(0);
    __builtin_amdgcn_s_barrier();
    __builtin_amdgcn_sched_barrier(0);

    const u16* P = &SM[bp * 32768];
    __builtin_amdgcn_s_setprio(1);
#pragma unroll
    for (int ks = 0; ks < 2; ++ks) {
      s16x8 a_h[2], a_l[2], b_h[2], b_l[2];
#pragma unroll
      for (int fm = 0; fm < 2; ++fm) {
        a_h[fm] = *(const s16x8*)&P[aoff(fm, ks)];
        a_l[fm] = *(const s16x8*)&P[8192 + aoff(fm, ks)];
      }
      // --- Q sub-phase ---
#pragma unroll
      for (int fn = 0; fn < 2; ++fn) {
        b_h[fn] = *(const s16x8*)&P[16384 + boff(fn, ks)];
        b_l[fn] = *(const s16x8*)&P[20480 + boff(fn, ks)];
      }
#pragma unroll
      for (int fm = 0; fm < 2; ++fm)
#pragma unroll
        for (int fn = 0; fn < 2; ++fn) {
          accq[fm][fn] = MFMA32(a_h[fm], b_h[fn], accq[fm][fn]);
          accq[fm][fn] = MFMA32(a_h[fm], b_l[fn], accq[fm][fn]);
          accq[fm][fn] = MFMA32(a_l[fm], b_h[fn], accq[fm][fn]);
        }
      // --- K sub-phase ---
#pragma unroll
      for (int fn = 0; fn < 2; ++fn) {
        b_h[fn] = *(const s16x8*)&P[24576 + boff(fn, ks)];
        b_l[fn] = *(const s16x8*)&P[28672 + boff(fn, ks)];
      }
#pragma unroll
      for (int fm = 0; fm < 2; ++fm)
#pragma unroll
        for (int fn = 0; fn < 2; ++fn) {
          acck[fm][fn] = MFMA32(a_h[fm], b_h[fn], acck[fm][fn]);
          acck[fm][fn] = MFMA32(a_h[fm], b_l[fn], acck[fm][fn]);
          acck[fm][fn] = MFMA32(a_l[fm], b_h[fn], acck[fm][fn]);
        }
    }
    __builtin_amdgcn_s_setprio(0);
    __builtin_amdgcn_s_barrier();
    bp ^= 1;
  }

  // ---- epilogue: RoPE both outputs, shared tables ----
  const int hd = 32 * wn + l31;
#pragma unroll
  for (int fm = 0; fm < 2; ++fm)
#pragma unroll
    for (int r = 0; r < 16; ++r) {
      const int row = bm * 256 + 64 * wm + 32 * fm + (r & 3) + 8 * (r >> 2) + 4 * hi;
      const int s = row & 2047;
      const float cs = cosT[s * 64 + hd], sn = sinT[s * 64 + hd];
      const size_t p1 = (size_t)row * N + bn * 128 + hd;
      {
        const float q1 = accq[fm][0][r], q2 = accq[fm][1][r];
        const float o1 = (q1 * cs - q2 * sn) * qscale;
        const float o2 = (q2 * cs + q1 * sn) * qscale;
        const u16 h1 = f2bf(o1);
        Qh[p1] = h1; Ql[p1] = f2bf(o1 - bf2f(h1));
        const u16 h2 = f2bf(o2);
        Qh[p1 + 64] = h2; Ql[p1 + 64] = f2bf(o2 - bf2f(h2));
      }
      {
        const float k1 = acck[fm][0][r], k2 = acck[fm][1][r];
        const float o1 = k1 * cs - k2 * sn;
        const float o2 = k2 * cs + k1 * sn;
        const u16 h1 = f2bf(o1);
        Kh[p1] = h1; Kl[p1] = f2bf(o1 - bf2f(h1));
        const u16 h2 = f2bf(o2);
        Kh[p1 + 64] = h2; Kl[p1 + 64] = f2bf(o2 - bf2f(h2));
      }
    }
}

// ---------------------------------------------------------------------------
// gemm8:  C(MxN) = A(MxK) * B(NxK)^T, bf16 inputs, fp32 accumulate.
// (1-term uses only now: V^T and Wo projections.)  Unchanged from R10.
// ---------------------------------------------------------------------------
template <int NTERM, int OMODE, int ROPE, int GX>
__global__ __launch_bounds__(512, NTERM == 3 ? 1 : 4)
void gemm8(const u16* __restrict__ Ah, const u16* __restrict__ Al,
           const u16* __restrict__ Bh, const u16* __restrict__ Bl,
           float* __restrict__ Cf, u16* __restrict__ Ch, u16* __restrict__ Cl,
           const float* __restrict__ cosT, const float* __restrict__ sinT,
           float scale, int M, int N, int K) {
  constexpr int BUF = (NTERM == 3) ? 24576 : 12288;   // u16 per buffer
  constexpr int BHI = (NTERM == 3) ? 16384 : 8192;    // B-hi region base
  constexpr int PER = GX / 8;                          // bn per XCD
  constexpr int PSH = (PER == 2) ? 1 : 2;
  static_assert(PER == 2 || PER == 4, "grid.x must be 16 or 32");
  __shared__ u16 SM[3 * BUF];
  const int t = threadIdx.x;
  const int w = t >> 6, lane = t & 63;
  const int l31 = lane & 31, hi = lane >> 5;
  const int wm = w >> 1, wn = w & 1;

  // ---- XCD-locality remap ----
  const int bid = (int)blockIdx.x + GX * (int)blockIdx.y;
  const int xcd = bid & 7, slot = bid >> 3;
  const int bn = PER * xcd + (slot & (PER - 1));
  const int bm = slot >> PSH;

  const size_t arow0 = (size_t)bm * 256, brow0 = (size_t)bn * 128;

  // ---- staging: linear LDS dest, pre-swizzled global source ----
  const int pA0 = 128 * w + lane;          // 16B-chunk index within A region
  const int pA1 = pA0 + 64;
  const int pB0 = 64 * w + lane;
  const int qA0 = pA0 ^ ((pA0 >> 3) & 7);
  const int qA1 = pA1 ^ ((pA1 >> 3) & 7);
  const int qB0 = pB0 ^ ((pB0 >> 3) & 7);
  const size_t gA0 = (arow0 + (qA0 >> 2)) * (size_t)K + (qA0 & 3) * 8;
  const size_t gA1 = (arow0 + (qA1 >> 2)) * (size_t)K + (qA1 & 3) * 8;
  const size_t gB0 = (brow0 + (qB0 >> 2)) * (size_t)K + (qB0 & 3) * 8;

  auto stage = [&](int k0, int bp) {
    u16* P = &SM[bp * BUF];
    gld16(&Ah[gA0 + k0], P + 1024 * w);
    gld16(&Ah[gA1 + k0], P + 1024 * w + 512);
    gld16(&Bh[gB0 + k0], P + BHI + 512 * w);
    if constexpr (NTERM == 3) {
      gld16(&Al[gA0 + k0], P + 8192 + 1024 * w);
      gld16(&Al[gA1 + k0], P + 8192 + 1024 * w + 512);
      gld16(&Bl[gB0 + k0], P + BHI + 4096 + 512 * w);
    }
  };

  // ---- swizzled read offsets (u16 units, within region) ----
  auto aoff = [&](int fm, int ks) {
    int q = ((64 * wm + 32 * fm + l31) << 2) | (2 * ks + hi);
    q ^= (q >> 3) & 7;
    return q * 8;
  };
  auto boff = [&](int fn, int ks) {
    int q = ((32 * wn + 64 * fn + l31) << 2) | (2 * ks + hi);
    q ^= (q >> 3) & 7;
    return q * 8;
  };

  f32x16 acc[2][2];
#pragma unroll
  for (int fm = 0; fm < 2; ++fm)
#pragma unroll
    for (int fn = 0; fn < 2; ++fn)
#pragma unroll
      for (int r = 0; r < 16; ++r) acc[fm][fn][r] = 0.f;

  const int NK = K >> 5;
  stage(0, 0);
  if (NK > 1) stage(32, 1);
  int cur = 0, nxt = 1, fut = 2;
  for (int kt = 0; kt < NK; ++kt) {
    if (kt + 2 < NK) {
      stage((kt + 2) * 32, fut);
      if constexpr (NTERM == 3)
        asm volatile("s_waitcnt vmcnt(12)" ::: "memory");
      else
        asm volatile("s_waitcnt vmcnt(6)" ::: "memory");
    } else if (kt + 1 < NK) {
      if constexpr (NTERM == 3)
        asm volatile("s_waitcnt vmcnt(6)" ::: "memory");
      else
        asm volatile("s_waitcnt vmcnt(3)" ::: "memory");
    } else {
      asm volatile("s_waitcnt vmcnt(0)" ::: "memory");
    }
    __builtin_amdgcn_sched_barrier(0);
    __builtin_amdgcn_s_barrier();
    __builtin_amdgcn_sched_barrier(0);

    const u16* P = &SM[cur * BUF];
    __builtin_amdgcn_s_setprio(1);
#pragma unroll
    for (int ks = 0; ks < 2; ++ks) {
      s16x8 a_h[2], a_l[2], b_h[2], b_l[2];
#pragma unroll
      for (int fm = 0; fm < 2; ++fm) {
        a_h[fm] = *(const s16x8*)&P[aoff(fm, ks)];
        if constexpr (NTERM == 3)
          a_l[fm] = *(const s16x8*)&P[8192 + aoff(fm, ks)];
      }
#pragma unroll
      for (int fn = 0; fn < 2; ++fn) {
        b_h[fn] = *(const s16x8*)&P[BHI + boff(fn, ks)];
        if constexpr (NTERM == 3)
          b_l[fn] = *(const s16x8*)&P[BHI + 4096 + boff(fn, ks)];
      }
#pragma unroll
      for (int fm = 0; fm < 2; ++fm)
#pragma unroll
        for (int fn = 0; fn < 2; ++fn) {
          acc[fm][fn] = MFMA32(a_h[fm], b_h[fn], acc[fm][fn]);
          if constexpr (NTERM == 3) {
            acc[fm][fn] = MFMA32(a_h[fm], b_l[fn], acc[fm][fn]);
            acc[fm][fn] = MFMA32(a_l[fm], b_h[fn], acc[fm][fn]);
          }
        }
    }
    __builtin_amdgcn_s_setprio(0);
    __builtin_amdgcn_s_barrier();
    const int tmp = cur; cur = nxt; nxt = fut; fut = tmp;
  }

  // ---- epilogue ----
  if constexpr (ROPE) {
    // tile is head-aligned (BN=128 = one head). hd in [0,64) pairs with hd+64.
    const int hd = 32 * wn + l31;
#pragma unroll
    for (int fm = 0; fm < 2; ++fm)
#pragma unroll
      for (int r = 0; r < 16; ++r) {
        const int row = bm * 256 + 64 * wm + 32 * fm + (r & 3) + 8 * (r >> 2) + 4 * hi;
        const int s = row & 2047;
        const float cs = cosT[s * 64 + hd], sn = sinT[s * 64 + hd];
        const float q1 = acc[fm][0][r], q2 = acc[fm][1][r];
        const float o1 = (q1 * cs - q2 * sn) * scale;
        const float o2 = (q2 * cs + q1 * sn) * scale;
        const size_t p1 = (size_t)row * N + bn * 128 + hd;
        const u16 h1 = f2bf(o1);
        Ch[p1] = h1; Cl[p1] = f2bf(o1 - bf2f(h1));
        const u16 h2 = f2bf(o2);
        Ch[p1 + 64] = h2; Cl[p1 + 64] = f2bf(o2 - bf2f(h2));
      }
  } else {
#pragma unroll
    for (int fm = 0; fm < 2; ++fm)
#pragma unroll
      for (int fn = 0; fn < 2; ++fn)
#pragma unroll
        for (int r = 0; r < 16; ++r) {
          const int row = bm * 256 + 64 * wm + 32 * fm + (r & 3) + 8 * (r >> 2) + 4 * hi;
          const int col = bn * 128 + 32 * wn + 64 * fn + l31;
          const float v = acc[fm][fn][r];
          if constexpr (OMODE == 0) {
            Cf[(size_t)row * N + col] = v;
          } else if constexpr (OMODE == 1) {
            const u16 hv = f2bf(v);
            Ch[(size_t)row * N + col] = hv;
            Cl[(size_t)row * N + col] = f2bf(v - bf2f(hv));
          } else {
            Ch[(size_t)row * N + col] = f2bf(v);
          }
        }
  }
}

// ---------------------------------------------------------------------------
// Flash attention, causal, 32x32x16 swapped-operand MFMA, counted-vmcnt
// double-buffered pipeline, QBLK=128, k-split wave pairs.  (unchanged R8)
// ---------------------------------------------------------------------------
__global__ __launch_bounds__(512, 2)
void attn(const u16* __restrict__ Qh, const u16* __restrict__ Ql,
          const u16* __restrict__ Kh, const u16* __restrict__ Kl,
          const u16* __restrict__ Vt, u16* __restrict__ Ctx) {
  __shared__ u16 SMEM[65536];               // 128 KB
  // buf p at u16 p*24576: Kh [0,8192) Kl [8192,16384) V [16384,24576)
  // scratch at u16 49152 (32 KB): m/l exchange, then O exchange, then Os

  const int t = threadIdx.x;
  const int w = t >> 6, lane = t & 63;
  const int l31 = lane & 31, hi = lane >> 5;
  const int swz = (l31 & 7) << 3;
  const int j = w >> 1, kh = w & 1;         // q-slice, k-half

  // ---- XCD remap: 16 blocks of a head on one XCD; unique task pairs ----
  const int bid = (int)blockIdx.x + 8 * (int)blockIdx.y + 128 * (int)blockIdx.z;
  const int xcd = bid & 7, slot = bid >> 3;          // slot 0..31
  const int h = xcd * 2 + (slot >> 4);
  const int rem = slot & 15;
  const int qtA = rem & 7, bA = rem >> 3;            // task A: (bA, qtA)
  // task B: (1-bA, 15-qtA).  Coverage: qt<=7 via A, qt>=8 via B, each once.

  // ---- staging source offsets (u16 units), pre-swizzled ----
  const int offK0 = (8 * w + (lane >> 4)) * 2048 + (((lane & 15) ^ ((lane >> 4) & 7)) * 8);
  const int offK1 = (8 * w + 4 + (lane >> 4)) * 2048 + (((lane & 15) ^ ((4 + (lane >> 4)) & 7)) * 8);
  const int offV0 = (16 * w + (lane >> 3)) * 4096 + (((lane & 7) ^ ((lane >> 3) & 7)) * 8);
  const int offV1 = offV0 + 8 * 4096;

  auto stage = [&](const u16* gK, const u16* gKlo, const u16* gV, int kt, int bp) {
    u16* B = &SMEM[bp * 24576];
    const int ka = kt * 131072;   // kt*64*2048
    const int va = kt * 64;
    gld16(gK + ka + offK0, B + 1024 * w);
    gld16(gK + ka + offK1, B + 1024 * w + 512);
    gld16(gKlo + ka + offK0, B + 8192 + 1024 * w);
    gld16(gKlo + ka + offK1, B + 8192 + 1024 * w + 512);
    gld16(gV + va + offV0, B + 16384 + 1024 * w);
    gld16(gV + va + offV1, B + 16384 + 1024 * w + 512);
  };

  int bufph = 0;
  // prime: task A tile 0
  {
    const u16* gK0 = Kh + ((size_t)(bA * 2048)) * 2048 + h * 128;
    const u16* gL0 = Kl + ((size_t)(bA * 2048)) * 2048 + h * 128;
    const u16* gV0 = Vt + (size_t)(h * 128) * 4096 + bA * 2048;
    stage(gK0, gL0, gV0, 0, 0);
  }

  for (int task = 0; task < 2; ++task) {
    const int qt = task ? 15 - qtA : qtA;
    const int bb = task ? 1 - bA : bA;
    const u16* gK0 = Kh + ((size_t)(bb * 2048)) * 2048 + h * 128;
    const u16* gL0 = Kl + ((size_t)(bb * 2048)) * 2048 + h * 128;
    const u16* gV0 = Vt + (size_t)(h * 128) * 4096 + bb * 2048;
    // next task's pointers (for cross-task prefetch)
    const int nb = 1 - bb;
    const u16* nK0 = Kh + ((size_t)(nb * 2048)) * 2048 + h * 128;
    const u16* nL0 = Kl + ((size_t)(nb * 2048)) * 2048 + h * 128;
    const u16* nV0 = Vt + (size_t)(h * 128) * 4096 + nb * 2048;

    const int q0 = qt * 128 + 32 * j;          // wave's first q row
    const int qg = q0 + l31;                   // this lane's q row
    // ---- Q fragments ----
    s16x8 qfh[8], qfl[8];
    {
      const size_t qbase = ((size_t)(bb * 2048 + qg)) * 2048 + h * 128 + 8 * hi;
#pragma unroll
      for (int s = 0; s < 8; ++s) {
        qfh[s] = *(const s16x8*)&Qh[qbase + 16 * s];
        qfl[s] = *(const s16x8*)&Ql[qbase + 16 * s];
      }
    }

    float m_run = -3.0e38f, l_run = 0.f;
    f32x16 o[4];
#pragma unroll
    for (int d = 0; d < 4; ++d)
#pragma unroll
      for (int r = 0; r < 16; ++r) o[d][r] = 0.f;

    const int nt = 2 * qt + 2;
    for (int kt = 0; kt < nt; ++kt) {
      // ---- issue next stage (stays in flight across barriers) ----
      bool staged = true;
      if (kt + 1 < nt)      stage(gK0, gL0, gV0, kt + 1, bufph ^ 1);
      else if (task == 0)   stage(nK0, nL0, nV0, 0, bufph ^ 1);
      else                  staged = false;
      if (staged) asm volatile("s_waitcnt vmcnt(6)" ::: "memory");
      else        asm volatile("s_waitcnt vmcnt(0)" ::: "memory");
      __builtin_amdgcn_sched_barrier(0);
      __builtin_amdgcn_s_barrier();
      __builtin_amdgcn_sched_barrier(0);

      const int kb0 = kt * 64 + 32 * kh;       // wave's k-half base
      const bool active = (q0 + 31) >= kb0;
      if (active) {
        const u16* Kb = &SMEM[bufph * 24576];
        const u16* Lb = Kb + 8192;
        const u16* Vb = Kb + 16384;
        // ---- S^T (wave's 32k x 32q block), split precision 3-term ----
        f32x16 acc;
#pragma unroll
        for (int r = 0; r < 16; ++r) acc[r] = 0.f;
        __builtin_amdgcn_s_setprio(1);
#pragma unroll
        for (int s = 0; s < 8; ++s) {
          const int col = 16 * s + 8 * hi;
          const s16x8 kha = *(const s16x8*)&Kb[((32 * kh + l31) * 128 + col) ^ swz];
          const s16x8 kla = *(const s16x8*)&Lb[((32 * kh + l31) * 128 + col) ^ swz];
          acc = MFMA32(kha, qfh[s], acc);
          acc = MFMA32(kla, qfh[s], acc);
          acc = MFMA32(kha, qfl[s], acc);
        }
        __builtin_amdgcn_s_setprio(0);

        // ---- causal mask + online softmax (lane-local, wave-private) ----
        const bool partial = (kb0 + 31) > q0;
        float mx = -3.0e38f;
#pragma unroll
        for (int r = 0; r < 16; ++r) {
          const int koff = (r & 3) + 8 * (r >> 2) + 4 * hi;
          float v = acc[r];
          if (partial && (kb0 + koff > qg)) v = -3.0e38f;
          acc[r] = v;
          mx = fmaxf(mx, v);
        }
        mx = fmaxf(mx, __shfl_xor(mx, 32));    // combine hi halves (same q)
        const float mn = fmaxf(m_run, mx);
        const float al = __expf(m_run - mn);
        m_run = mn;
        float rs = 0.f;
#pragma unroll
        for (int r = 0; r < 16; ++r) {
          const float e = __expf(acc[r] - mn);
          acc[r] = e;
          rs += e;
        }
        rs += __shfl_xor(rs, 32);
        l_run = l_run * al + rs;
#pragma unroll
        for (int d = 0; d < 4; ++d)
#pragma unroll
          for (int r = 0; r < 16; ++r) o[d][r] *= al;

        // ---- pack P -> PV B-fragments (cvt_pk + permlane32_swap) ----
        s16x8 pb[2];
#pragma unroll
        for (int tt = 0; tt < 2; ++tt) {
          const int q2A = 2 * tt;
          const float e0 = acc[4 * q2A + 0], e1 = acc[4 * q2A + 1];
          const float e2 = acc[4 * q2A + 2], e3 = acc[4 * q2A + 3];
          const float f0 = acc[4 * q2A + 4], f1 = acc[4 * q2A + 5];
          const float f2 = acc[4 * q2A + 6], f3 = acc[4 * q2A + 7];
          unsigned a0 = cvtpk_bf16(e0, e1);
          unsigned a1 = cvtpk_bf16(e2, e3);
          unsigned b0 = cvtpk_bf16(f0, f1);
          unsigned b1 = cvtpk_bf16(f2, f3);
          asm volatile("v_permlane32_swap_b32 %0, %1" : "+v"(a0), "+v"(b0));
          asm volatile("v_permlane32_swap_b32 %0, %1" : "+v"(a1), "+v"(b1));
          union { unsigned u[4]; s16x8 v; } pk;
          pk.u[0] = a0; pk.u[1] = a1; pk.u[2] = b0; pk.u[3] = b1;
          pb[tt] = pk.v;
        }

        // ---- O^T += V^T[:, wave's k-half] * P ----
        __builtin_amdgcn_s_setprio(1);
#pragma unroll
        for (int d = 0; d < 4; ++d) {
#pragma unroll
          for (int tt = 0; tt < 2; ++tt) {
            const s16x8 va = *(const s16x8*)
                &Vb[((32 * d + l31) * 64 + 16 * (2 * kh + tt) + 8 * hi) ^ swz];
            o[d] = MFMA32(va, pb[tt], o[d]);
          }
        }
        __builtin_amdgcn_s_setprio(0);
      }
      __builtin_amdgcn_s_barrier();
      bufph ^= 1;
    }

    // ======== epilogue: merge k-half wave pairs, normalize, store ========
    float* Sf = (float*)&SMEM[49152];          // 32KB scratch as f32[8192]
    // (1) m/l exchange
    Sf[w * 64 + lane] = m_run;
    Sf[512 + w * 64 + lane] = l_run;
    asm volatile("s_waitcnt lgkmcnt(0)" ::: "memory");
    __builtin_amdgcn_s_barrier();
    const float mOth = Sf[(w ^ 1) * 64 + lane];
    const float lOth = Sf[512 + (w ^ 1) * 64 + lane];
    const float mC = fmaxf(m_run, mOth);
    const float eS = __expf(m_run - mC);
    const float eO = __expf(mOth - mC);
    const float lC = eS * l_run + eO * lOth;
    // scale own partial O (odd waves hand over pre-scaled)
#pragma unroll
    for (int d = 0; d < 4; ++d)
#pragma unroll
      for (int r = 0; r < 16; ++r) o[d][r] *= eS;
    __builtin_amdgcn_s_barrier();              // m/l reads done before reuse
    // (2) O exchange: odd wave -> even wave, 2 rounds of 32KB
#pragma unroll
    for (int round = 0; round < 2; ++round) {
      if ((w >> 2) == round && kh == 1) {
        const int sl = j & 1;
#pragma unroll
        for (int d = 0; d < 4; ++d)
#pragma unroll
          for (int rr = 0; rr < 4; ++rr) {
            float4v c;
            c[0] = o[d][4 * rr + 0]; c[1] = o[d][4 * rr + 1];
            c[2] = o[d][4 * rr + 2]; c[3] = o[d][4 * rr + 3];
            const int cidx = 4 * (d * 4 + rr);
            *(float4v*)&Sf[sl * 4096 + ((lane * 64 + cidx) ^ ((lane & 7) << 2))] = c;
          }
      }
      asm volatile("s_waitcnt lgkmcnt(0)" ::: "memory");
      __builtin_amdgcn_s_barrier();
      if ((w >> 2) == round && kh == 0) {
        const int sl = j & 1;
#pragma unroll
        for (int d = 0; d < 4; ++d)
#pragma unroll
          for (int rr = 0; rr < 4; ++rr) {
            const int cidx = 4 * (d * 4 + rr);
            const float4v c =
                *(const float4v*)&Sf[sl * 4096 + ((lane * 64 + cidx) ^ ((lane & 7) << 2))];
            o[d][4 * rr + 0] += c[0]; o[d][4 * rr + 1] += c[1];
            o[d][4 * rr + 2] += c[2]; o[d][4 * rr + 3] += c[3];
          }
      }
      __builtin_amdgcn_s_barrier();
    }
    // (3) even waves: normalize + transposed bf16 write to Os
    u16* Os = &SMEM[49152];                    // [128][128] u16, swizzled
    if (kh == 0) {
      const float inv_l = 1.0f / lC;
      const int rl = 32 * j + l31;
#pragma unroll
      for (int d = 0; d < 4; ++d)
#pragma unroll
        for (int r = 0; r < 16; r += 2) {
          const int dd = 32 * d + (r & 3) + 8 * (r >> 2) + 4 * hi;
          const unsigned pr = cvtpk_bf16(o[d][r] * inv_l, o[d][r + 1] * inv_l);
          *(unsigned*)&Os[(rl * 128 + dd) ^ ((rl & 7) << 3)] = pr;
        }
    }
    asm volatile("s_waitcnt lgkmcnt(0)" ::: "memory");
    __builtin_amdgcn_s_barrier();
    // (4) coalesced store, all 8 waves
    {
      const int rr = t >> 2, cb = (t & 3) * 32;
      const size_t ob =
          ((size_t)(bb * 2048 + qt * 128 + rr)) * 2048 + h * 128 + cb;
#pragma unroll
      for (int p = 0; p < 4; ++p)
        *(u16x8*)&Ctx[ob + 8 * p] =
            *(const u16x8*)&Os[(rr * 128 + cb + 8 * p) ^ ((rr & 7) << 3)];
    }
    asm volatile("s_waitcnt lgkmcnt(0)" ::: "memory");
    __builtin_amdgcn_s_barrier();
  }
}

// ---------------------------------------------------------------------------
extern "C" void kernel_launch(void* const* d_in, const int* in_sizes, int n_in,
                              void* d_out, int out_size, void* d_ws, size_t ws_size,
                              hipStream_t stream) {
  const float* x  = (const float*)d_in[0];
  const float* Wq = (const float*)d_in[1];
  const float* Wk = (const float*)d_in[2];
  const float* Wv = (const float*)d_in[3];
  const float* Wo = (const float*)d_in[4];
  float* out = (float*)d_out;

  char* ws = (char*)d_ws;
  size_t off = 0;
  auto alloc = [&](size_t bytes) {
    char* p = ws + off;
    off += (bytes + 255) & ~(size_t)255;
    return p;
  };
  const size_t XE = (size_t)4096 * 2048;   // B*S x H elements
  const size_t WE = (size_t)2048 * 2048;

  u16* xh  = (u16*)alloc(XE * 2);
  u16* xl  = (u16*)alloc(XE * 2);
  u16* Wqh = (u16*)alloc(WE * 2);
  u16* Wql = (u16*)alloc(WE * 2);
  u16* Wkh = (u16*)alloc(WE * 2);
  u16* Wkl = (u16*)alloc(WE * 2);
  u16* Wvh = (u16*)alloc(WE * 2);
  u16* Woh = (u16*)alloc(WE * 2);
  u16* Qhb = (u16*)alloc(XE * 2);
  u16* Qlb = (u16*)alloc(XE * 2);
  u16* Khb = (u16*)alloc(XE * 2);
  u16* Klb = (u16*)alloc(XE * 2);
  u16* Vtb = (u16*)alloc(XE * 2);   // V^T: [2048 dims][4096 seq]
  u16* Ctxb = (u16*)alloc(XE * 2);
  float* cosT = (float*)alloc((size_t)2048 * 64 * 4);
  float* sinT = (float*)alloc((size_t)2048 * 64 * 4);
  (void)ws_size;  // requires ~170 MB of workspace
  (void)in_sizes; (void)n_in; (void)out_size;

  // 1) precision split + RoPE tables
  split_bf16<<<8192, 256, 0, stream>>>(x, xh, xl, (int)(XE / 4));
  split_bf16<<<4096, 256, 0, stream>>>(Wq, Wqh, Wql, (int)(WE / 4));
  split_bf16<<<4096, 256, 0, stream>>>(Wk, Wkh, Wkl, (int)(WE / 4));
  split_bf16<<<4096, 256, 0, stream>>>(Wv, Wvh, nullptr, (int)(WE / 4));
  split_bf16<<<4096, 256, 0, stream>>>(Wo, Woh, nullptr, (int)(WE / 4));
  rope_tab<<<512, 256, 0, stream>>>(cosT, sinT);

  // 2) fused Q+K projection (shared A staging, shared RoPE tables)
  gemm_qk<<<dim3(16, 16), 512, 0, stream>>>(
      xh, xl, Wqh, Wql, Wkh, Wkl, Qhb, Qlb, Khb, Klb, cosT, sinT,
      11.313708498984760f, 4096, 2048, 2048);
  // V^T = Wv * x^T :  A=Wv (M=2048 dims), B=x (N=4096 seq)
  gemm8<1, 2, 0, 32><<<dim3(32, 8), 512, 0, stream>>>(
      Wvh, nullptr, xh, nullptr, nullptr, Vtb, nullptr, nullptr, nullptr,
      1.0f, 2048, 4096, 2048);

  // 3) causal flash attention (de-duped task map, k-split wave pairs)
  attn<<<dim3(8, 16, 2), 512, 0, stream>>>(Qhb, Qlb, Khb, Klb, Vtb, Ctxb);

  // 4) output projection -> fp32 d_out
  gemm8<1, 0, 0, 16><<<dim3(16, 16), 512, 0, stream>>>(
      Ctxb, nullptr, Woh, nullptr, out, nullptr, nullptr, nullptr, nullptr,
      1.0f, 4096, 2048, 2048);
}